// Round 6
// baseline (493.770 us; speedup 1.0000x reference)
//
#include <hip/hip_runtime.h>
#include <hip/hip_bf16.h>

// GCN: 3x gcn_conv + mean-pool + linear, bf16 MFMA pipeline.
// out[i] = dinv[i] * (sum_{e: dst=i} g[src_e] + g[i]) + b,  g = dinv .* (x @ W)

typedef __attribute__((ext_vector_type(8))) short short8_t;
typedef __attribute__((ext_vector_type(4))) float float4_t;

__device__ __forceinline__ unsigned short f2bf(float f) {
    unsigned int u = __float_as_uint(f);
    u += 0x7FFFu + ((u >> 16) & 1u);   // round-to-nearest-even
    return (unsigned short)(u >> 16);
}
__device__ __forceinline__ float bf2f(unsigned short h) {
    return __uint_as_float(((unsigned int)h) << 16);
}

// async global->LDS, 16B per lane; LDS dest is wave-uniform base + lane*16 (m104/m108)
#define GLDS16(gp, lp)                                                          \
    __builtin_amdgcn_global_load_lds(                                           \
        (const __attribute__((address_space(1))) void*)(gp),                    \
        (__attribute__((address_space(3))) void*)(lp), 16, 0, 0)

// ---------------- converts ----------------

__global__ __launch_bounds__(256) void conv_x_k(const float* __restrict__ x,
                                                ushort* __restrict__ Xb,
                                                int M, int Mpad) {
    int t = blockIdx.x * 256 + threadIdx.x;  // one float4 -> ushort4
    int total = Mpad * 128;                  // 512/4 per row
    if (t >= total) return;
    int row = t >> 7;
    ushort4 o;
    if (row < M) {
        float4 v = ((const float4*)x)[t];
        o.x = f2bf(v.x); o.y = f2bf(v.y); o.z = f2bf(v.z); o.w = f2bf(v.w);
    } else {
        o.x = o.y = o.z = o.w = 0;
    }
    ((ushort4*)Xb)[t] = o;
}

// all three weights, fused: W fp32 [K][N] -> Wt bf16 [Npad][K]
__global__ void conv_weights(const float* __restrict__ W1, ushort* __restrict__ Wt1,
                             const float* __restrict__ W2, ushort* __restrict__ Wt2,
                             const float* __restrict__ W3, ushort* __restrict__ Wt3) {
    int t = blockIdx.x * 256 + threadIdx.x;
    if (t < 131072) {                       // Wt1 [256][512], N=256
        int k = t & 511, n = t >> 9;
        Wt1[t] = f2bf(W1[(size_t)k * 256 + n]);
    } else if (t < 163840) {                // Wt2 [128][256], N=128
        int u = t - 131072;
        int k = u & 255, n = u >> 8;
        Wt2[u] = f2bf(W2[(size_t)k * 128 + n]);
    } else if (t < 180224) {                // Wt3 [128][128], N=64 (rows 64.. zero)
        int u = t - 163840;
        int k = u & 127, n = u >> 7;
        Wt3[u] = (n < 64) ? f2bf(W3[(size_t)k * 64 + n]) : (ushort)0;
    }
}

// ---------------- CSR build ----------------

__global__ void count_indeg(const int* __restrict__ dst, int* __restrict__ indeg, int E) {
    int e = blockIdx.x * blockDim.x + threadIdx.x;
    if (e < E) atomicAdd(&indeg[dst[e]], 1);
}

// hierarchical scan: per-1024-chunk inclusive -> chunk totals -> combine
__global__ __launch_bounds__(1024) void scan1(const int* __restrict__ indeg,
                                              int* __restrict__ incl,   // rowptr as temp
                                              int* __restrict__ part, int n) {
    __shared__ int sm[1024];
    int i = blockIdx.x * 1024 + threadIdx.x;
    int v = (i < n) ? indeg[i] : 0;
    sm[threadIdx.x] = v;
    __syncthreads();
    #pragma unroll
    for (int off = 1; off < 1024; off <<= 1) {
        int t = (threadIdx.x >= (unsigned)off) ? sm[threadIdx.x - off] : 0;
        __syncthreads();
        sm[threadIdx.x] += t;
        __syncthreads();
    }
    if (i < n) incl[i] = sm[threadIdx.x];
    if (threadIdx.x == 1023) part[blockIdx.x] = sm[1023];
}

__global__ void scan2(int* __restrict__ part, int nb) {
    int t = threadIdx.x;  // 64
    int v = (t < nb) ? part[t] : 0;
    int orig = v;
    #pragma unroll
    for (int off = 1; off < 64; off <<= 1) {
        int u = __shfl_up(v, off, 64);
        if (t >= off) v += u;
    }
    if (t < nb) part[t] = v - orig;  // exclusive chunk offset
}

__global__ void scan3(const int* __restrict__ indeg, int* __restrict__ rowptr,
                      int* __restrict__ cursor, const int* __restrict__ part,
                      float* __restrict__ dinv, int n, int E) {
    int i = blockIdx.x * blockDim.x + threadIdx.x;
    if (i < n) {
        int excl = rowptr[i] - indeg[i] + part[i >> 10];
        rowptr[i] = excl;
        cursor[i] = excl;
        dinv[i] = rsqrtf((float)indeg[i] + 1.0f);  // +1 self-loop
    }
    if (i == 0) rowptr[n] = E;
}

__global__ void fill_csr(const int* __restrict__ src, const int* __restrict__ dst,
                         int* __restrict__ cursor, int* __restrict__ col, int E) {
    int e = blockIdx.x * blockDim.x + threadIdx.x;
    if (e < E) {
        int p = atomicAdd(&cursor[dst[e]], 1);
        col[p] = src[e];
    }
}

// ---------------- bf16 MFMA GEMM: C[m,n] = dinv[m] * sum_k A[m,k]*Bt[n,k] ----------------
// 128x128 tile, 256 threads = 4 waves (2x2), each wave 4x4 tiles of 16x16x32.
// Staging via global_load_lds width=16 (m97 structure): per iter, 4 async DMA
// instructions stage the 128x32 A and B tiles. A must be padded to Mpad rows.

__global__ __launch_bounds__(256) void gemm_mfma(const ushort* __restrict__ A,
                                                 const ushort* __restrict__ Bt,
                                                 const float* __restrict__ dinv,
                                                 ushort* __restrict__ C,
                                                 int M, int Ncols, int K, int ldc) {
    __shared__ __align__(16) ushort As[128 * 32];
    __shared__ __align__(16) ushort Bs[128 * 32];
    int tid = threadIdx.x;
    int lane = tid & 63, w = tid >> 6;
    int wr = w >> 1, wc = w & 1;
    int bm = blockIdx.x * 128, bn = blockIdx.y * 128;

    float4_t acc[4][4];
    #pragma unroll
    for (int i = 0; i < 4; ++i)
        #pragma unroll
        for (int j = 0; j < 4; ++j) acc[i][j] = (float4_t)0.0f;

    // staging addresses: lane covers row (tid>>2), k-chunk (tid&3)*8 (16 B);
    // LDS dest = wave-uniform base + lane*16 == byte offset tid*16: row-major 128x32 tile.
    int r0 = tid >> 2;
    int kb = (tid & 3) * 8;
    const ushort* ga0 = A + (size_t)(bm + r0) * K + kb;
    const ushort* ga1 = A + (size_t)(bm + r0 + 64) * K + kb;
    const ushort* gb0 = Bt + (size_t)(bn + r0) * K + kb;
    const ushort* gb1 = Bt + (size_t)(bn + r0 + 64) * K + kb;
    ushort* lA0 = As + w * 512;          // wave-uniform
    ushort* lA1 = As + 2048 + w * 512;
    ushort* lB0 = Bs + w * 512;
    ushort* lB1 = Bs + 2048 + w * 512;

    int arow = wr * 64 + (lane & 15);
    int brow = wc * 64 + (lane & 15);
    int quad = lane >> 4;

    for (int k0 = 0; k0 < K; k0 += 32) {
        __syncthreads();  // previous iter's LDS readers done
        GLDS16(ga0 + k0, lA0);
        GLDS16(ga1 + k0, lA1);
        GLDS16(gb0 + k0, lB0);
        GLDS16(gb1 + k0, lB1);
        __syncthreads();  // vmcnt drained -> tiles visible
        short8_t aF[4], bF[4];
        #pragma unroll
        for (int i = 0; i < 4; ++i)
            aF[i] = *(const short8_t*)&As[(arow + i * 16) * 32 + quad * 8];
        #pragma unroll
        for (int j = 0; j < 4; ++j)
            bF[j] = *(const short8_t*)&Bs[(brow + j * 16) * 32 + quad * 8];
        #pragma unroll
        for (int i = 0; i < 4; ++i)
            #pragma unroll
            for (int j = 0; j < 4; ++j)
                acc[i][j] = __builtin_amdgcn_mfma_f32_16x16x32_bf16(aF[i], bF[j], acc[i][j], 0, 0, 0);
    }

    // C/D layout: col = lane&15, row = (lane>>4)*4 + reg
    int colb = bn + wc * 64 + (lane & 15);
    #pragma unroll
    for (int i = 0; i < 4; ++i) {
        int mb = bm + wr * 64 + i * 16 + quad * 4;
        #pragma unroll
        for (int r = 0; r < 4; ++r) {
            int m = mb + r;
            if (m >= M) continue;
            float s = dinv[m];
            #pragma unroll
            for (int j = 0; j < 4; ++j) {
                int n = colb + j * 16;
                if (n < Ncols) C[(size_t)m * ldc + n] = f2bf(acc[i][j][r] * s);
            }
        }
    }
}

// ---------------- aggregation: one wave per node, bf16 in/out, 16-deep MLP ----------------

template <int F, bool RELU>
__global__ __launch_bounds__(256) void agg_bf(const ushort* __restrict__ g,
                                              const int* __restrict__ rowptr,
                                              const int* __restrict__ col,
                                              const float* __restrict__ dinv,
                                              const float* __restrict__ bias,
                                              ushort* __restrict__ out,
                                              int n, int npad) {
    constexpr int VPT = F / 64;
    int wid = (int)((blockIdx.x * blockDim.x + threadIdx.x) >> 6);
    int lane = threadIdx.x & 63;
    if (wid >= npad) return;
    int off = lane * VPT;
    ushort* orow = out + (size_t)wid * F + off;
    if (wid >= n) {  // zero padded tail rows (next GEMM reads them)
        #pragma unroll
        for (int j = 0; j < VPT; ++j) orow[j] = 0;
        return;
    }
    float acc[VPT];
    #pragma unroll
    for (int j = 0; j < VPT; ++j) acc[j] = 0.f;

    int e0 = rowptr[wid];
    int deg = rowptr[wid + 1] - e0;

    for (int base = 0; base < deg; base += 64) {
        int cnt = min(64, deg - base);
        int ec = (lane < cnt) ? col[e0 + base + lane] : 0;
        int j = 0;
        for (; j + 16 <= cnt; j += 16) {
            int s[16];
            #pragma unroll
            for (int u = 0; u < 16; ++u) s[u] = __shfl(ec, j + u);
            if constexpr (VPT == 4) {
                ushort4 v[16];
                #pragma unroll
                for (int u = 0; u < 16; ++u)
                    v[u] = *(const ushort4*)(g + (size_t)s[u] * F + off);
                #pragma unroll
                for (int u = 0; u < 16; ++u) {
                    acc[0] += bf2f(v[u].x); acc[1] += bf2f(v[u].y);
                    acc[2] += bf2f(v[u].z); acc[3] += bf2f(v[u].w);
                }
            } else if constexpr (VPT == 2) {
                ushort2 v[16];
                #pragma unroll
                for (int u = 0; u < 16; ++u)
                    v[u] = *(const ushort2*)(g + (size_t)s[u] * F + off);
                #pragma unroll
                for (int u = 0; u < 16; ++u) {
                    acc[0] += bf2f(v[u].x); acc[1] += bf2f(v[u].y);
                }
            } else {
                ushort v[16];
                #pragma unroll
                for (int u = 0; u < 16; ++u) v[u] = g[(size_t)s[u] * F + off];
                #pragma unroll
                for (int u = 0; u < 16; ++u) acc[0] += bf2f(v[u]);
            }
        }
        for (; j + 4 <= cnt; j += 4) {
            int s[4];
            #pragma unroll
            for (int u = 0; u < 4; ++u) s[u] = __shfl(ec, j + u);
            if constexpr (VPT == 4) {
                ushort4 v[4];
                #pragma unroll
                for (int u = 0; u < 4; ++u)
                    v[u] = *(const ushort4*)(g + (size_t)s[u] * F + off);
                #pragma unroll
                for (int u = 0; u < 4; ++u) {
                    acc[0] += bf2f(v[u].x); acc[1] += bf2f(v[u].y);
                    acc[2] += bf2f(v[u].z); acc[3] += bf2f(v[u].w);
                }
            } else if constexpr (VPT == 2) {
                ushort2 v[4];
                #pragma unroll
                for (int u = 0; u < 4; ++u)
                    v[u] = *(const ushort2*)(g + (size_t)s[u] * F + off);
                #pragma unroll
                for (int u = 0; u < 4; ++u) {
                    acc[0] += bf2f(v[u].x); acc[1] += bf2f(v[u].y);
                }
            } else {
                ushort v[4];
                #pragma unroll
                for (int u = 0; u < 4; ++u) v[u] = g[(size_t)s[u] * F + off];
                #pragma unroll
                for (int u = 0; u < 4; ++u) acc[0] += bf2f(v[u]);
            }
        }
        for (; j < cnt; ++j) {
            int s = __shfl(ec, j);
            const ushort* row = g + (size_t)s * F + off;
            if constexpr (VPT == 4) {
                ushort4 v = *(const ushort4*)row;
                acc[0] += bf2f(v.x); acc[1] += bf2f(v.y);
                acc[2] += bf2f(v.z); acc[3] += bf2f(v.w);
            } else if constexpr (VPT == 2) {
                ushort2 v = *(const ushort2*)row;
                acc[0] += bf2f(v.x); acc[1] += bf2f(v.y);
            } else {
                acc[0] += bf2f(row[0]);
            }
        }
    }

    const ushort* rowi = g + (size_t)wid * F + off;
    float di = dinv[wid];
    #pragma unroll
    for (int j = 0; j < VPT; ++j) {
        float v = di * (acc[j] + bf2f(rowi[j])) + bias[off + j];
        if (RELU) v = fmaxf(v, 0.f);
        orow[j] = f2bf(v);
    }
}

// ---------------- pooling + final linear ----------------

__global__ __launch_bounds__(256) void pool_sorted(const ushort* __restrict__ h,
                                                   const int* __restrict__ batch,
                                                   float* __restrict__ sums,
                                                   float* __restrict__ cnt, int n) {
    int wave = (int)((blockIdx.x * blockDim.x + threadIdx.x) >> 6);
    int lane = threadIdx.x & 63;
    int start = wave * 64;
    if (start >= n) return;
    int end = min(start + 64, n);
    float acc = 0.f;
    int cur = batch[start];
    int runlen = 0;
    for (int i = start; i < end; ++i) {
        int b = batch[i];
        if (b != cur) {
            atomicAdd(&sums[cur * 64 + lane], acc);
            if (lane == 0) atomicAdd(&cnt[cur], (float)runlen);
            acc = 0.f;
            runlen = 0;
            cur = b;
        }
        acc += bf2f(h[(size_t)i * 64 + lane]);
        runlen++;
    }
    atomicAdd(&sums[cur * 64 + lane], acc);
    if (lane == 0) atomicAdd(&cnt[cur], (float)runlen);
}

__global__ void final_lin(const float* __restrict__ sums, const float* __restrict__ cnt,
                          const float* __restrict__ Wl, const float* __restrict__ bl,
                          float* __restrict__ out) {
    int t = threadIdx.x;  // 128 threads: (graph, j)
    int g = t >> 1, j = t & 1;
    float c = fmaxf(cnt[g], 1.0f);
    float a = 0.f;
    #pragma unroll
    for (int k = 0; k < 64; ++k) a += sums[g * 64 + k] * Wl[k * 2 + j];
    out[t] = a / c + bl[j];
}

// ---------------- launch ----------------

extern "C" void kernel_launch(void* const* d_in, const int* in_sizes, int n_in,
                              void* d_out, int out_size, void* d_ws, size_t ws_size,
                              hipStream_t stream) {
    const float* x   = (const float*)d_in[0];
    const int*   ei  = (const int*)d_in[1];
    const int*   bat = (const int*)d_in[2];
    const float* W1  = (const float*)d_in[3];
    const float* b1  = (const float*)d_in[4];
    const float* W2  = (const float*)d_in[5];
    const float* b2  = (const float*)d_in[6];
    const float* W3  = (const float*)d_in[7];
    const float* b3  = (const float*)d_in[8];
    const float* Wl  = (const float*)d_in[9];
    const float* bl  = (const float*)d_in[10];
    float* out = (float*)d_out;

    const int N = in_sizes[0] / 512;
    const int E = in_sizes[1] / 2;
    const int Mpad = ((N + 127) / 128) * 128;   // 50048
    const int* src = ei;
    const int* dst = ei + E;

    char* w = (char*)d_ws;
    auto alloc = [&](size_t bytes) {
        char* p = w;
        w += (bytes + 255) & ~(size_t)255;
        return p;
    };
    ushort* Xb   = (ushort*)alloc((size_t)Mpad * 512 * 2);  // bf16 x (L3-resident)
    ushort* G    = (ushort*)alloc((size_t)Mpad * 256 * 2);  // gemm output
    ushort* H    = (ushort*)alloc((size_t)Mpad * 256 * 2);  // agg output
    ushort* Wt1  = (ushort*)alloc(256 * 512 * 2);
    ushort* Wt2  = (ushort*)alloc(128 * 256 * 2);
    ushort* Wt3  = (ushort*)alloc(128 * 128 * 2);
    float* dinv  = (float*)alloc((size_t)N * 4);
    int* rowptr  = (int*)alloc((size_t)(N + 1) * 4);
    int* cursor  = (int*)alloc((size_t)N * 4);
    int* col     = (int*)alloc((size_t)E * 4);
    int* part    = (int*)alloc(256 * 4);
    size_t zbytes = (size_t)N * 4 + 64 * 64 * 4 + 64 * 4;  // indeg + sums + cnt
    int* indeg   = (int*)alloc(zbytes);
    float* sums  = (float*)(indeg + N);
    float* cnt   = sums + 64 * 64;

    hipMemsetAsync(indeg, 0, zbytes, stream);

    // converts
    conv_x_k<<<(Mpad * 128 + 255) / 256, 256, 0, stream>>>(x, Xb, N, Mpad);
    conv_weights<<<(180224 + 255) / 256, 256, 0, stream>>>(W1, Wt1, W2, Wt2, W3, Wt3);

    // CSR
    count_indeg<<<(E + 255) / 256, 256, 0, stream>>>(dst, indeg, E);
    int nb = (N + 1023) / 1024;
    scan1<<<nb, 1024, 0, stream>>>(indeg, rowptr, part, N);
    scan2<<<1, 64, 0, stream>>>(part, nb);
    scan3<<<(N + 255) / 256, 256, 0, stream>>>(indeg, rowptr, cursor, part, dinv, N, E);
    fill_csr<<<(E + 255) / 256, 256, 0, stream>>>(src, dst, cursor, col, E);

    int npad = Mpad;
    // layer 1: 512 -> 256
    gemm_mfma<<<dim3(Mpad / 128, 2), 256, 0, stream>>>(Xb, Wt1, dinv, G, N, 256, 512, 256);
    agg_bf<256, true><<<npad / 4, 256, 0, stream>>>(G, rowptr, col, dinv, b1, H, N, npad);
    // layer 2: 256 -> 128
    gemm_mfma<<<dim3(Mpad / 128, 1), 256, 0, stream>>>(H, Wt2, dinv, G, N, 128, 256, 128);
    agg_bf<128, true><<<npad / 4, 256, 0, stream>>>(G, rowptr, col, dinv, b2, H, N, npad);
    // layer 3: 128 -> 64 (Wt3 padded to 128 rows, store guarded n<64)
    gemm_mfma<<<dim3(Mpad / 128, 1), 256, 0, stream>>>(H, Wt3, dinv, G, N, 64, 128, 64);
    agg_bf<64, false><<<npad / 4, 256, 0, stream>>>(G, rowptr, col, dinv, b3, H, N, npad);

    pool_sorted<<<(N + 255) / 256, 256, 0, stream>>>(H, bat, sums, cnt, N);
    final_lin<<<1, 128, 0, stream>>>(sums, cnt, Wl, bl, out);
}

// Round 7
// 488.664 us; speedup vs baseline: 1.0104x; 1.0104x over previous
//
#include <hip/hip_runtime.h>
#include <hip/hip_bf16.h>

// GCN: 3x gcn_conv + mean-pool + linear, bf16 MFMA pipeline.
// out[i] = dinv[i] * (sum_{e: dst=i} g[src_e] + g[i]) + b,  g = dinv .* (x @ W)

typedef __attribute__((ext_vector_type(8))) short short8_t;
typedef __attribute__((ext_vector_type(4))) float float4_t;

__device__ __forceinline__ unsigned short f2bf(float f) {
    unsigned int u = __float_as_uint(f);
    u += 0x7FFFu + ((u >> 16) & 1u);   // round-to-nearest-even
    return (unsigned short)(u >> 16);
}
__device__ __forceinline__ float bf2f(unsigned short h) {
    return __uint_as_float(((unsigned int)h) << 16);
}

// async global->LDS, 16B per lane; LDS dest is wave-uniform base + lane*16 (m104/m108)
#define GLDS16(gp, lp)                                                          \
    __builtin_amdgcn_global_load_lds(                                           \
        (const __attribute__((address_space(1))) void*)(gp),                    \
        (__attribute__((address_space(3))) void*)(lp), 16, 0, 0)

// ---------------- converts ----------------

__global__ __launch_bounds__(256) void conv_x_k(const float* __restrict__ x,
                                                ushort* __restrict__ Xb,
                                                int M, int Mpad) {
    int t = blockIdx.x * 256 + threadIdx.x;  // one float4 -> ushort4
    int total = Mpad * 128;                  // 512/4 per row
    if (t >= total) return;
    int row = t >> 7;
    ushort4 o;
    if (row < M) {
        float4 v = ((const float4*)x)[t];
        o.x = f2bf(v.x); o.y = f2bf(v.y); o.z = f2bf(v.z); o.w = f2bf(v.w);
    } else {
        o.x = o.y = o.z = o.w = 0;
    }
    ((ushort4*)Xb)[t] = o;
}

// all three weights, fused: W fp32 [K][N] -> Wt bf16 [Npad][K]
__global__ void conv_weights(const float* __restrict__ W1, ushort* __restrict__ Wt1,
                             const float* __restrict__ W2, ushort* __restrict__ Wt2,
                             const float* __restrict__ W3, ushort* __restrict__ Wt3) {
    int t = blockIdx.x * 256 + threadIdx.x;
    if (t < 131072) {                       // Wt1 [256][512], N=256
        int k = t & 511, n = t >> 9;
        Wt1[t] = f2bf(W1[(size_t)k * 256 + n]);
    } else if (t < 163840) {                // Wt2 [128][256], N=128
        int u = t - 131072;
        int k = u & 255, n = u >> 8;
        Wt2[u] = f2bf(W2[(size_t)k * 128 + n]);
    } else if (t < 180224) {                // Wt3 [128][128], N=64 (rows 64.. zero)
        int u = t - 163840;
        int k = u & 127, n = u >> 7;
        Wt3[u] = (n < 64) ? f2bf(W3[(size_t)k * 64 + n]) : (ushort)0;
    }
}

// ---------------- CSR build ----------------

__global__ void count_indeg(const int* __restrict__ dst, int* __restrict__ indeg, int E) {
    int e = blockIdx.x * blockDim.x + threadIdx.x;
    if (e < E) atomicAdd(&indeg[dst[e]], 1);
}

// hierarchical scan: per-1024-chunk inclusive -> chunk totals -> combine
__global__ __launch_bounds__(1024) void scan1(const int* __restrict__ indeg,
                                              int* __restrict__ incl,   // rowptr as temp
                                              int* __restrict__ part, int n) {
    __shared__ int sm[1024];
    int i = blockIdx.x * 1024 + threadIdx.x;
    int v = (i < n) ? indeg[i] : 0;
    sm[threadIdx.x] = v;
    __syncthreads();
    #pragma unroll
    for (int off = 1; off < 1024; off <<= 1) {
        int t = (threadIdx.x >= (unsigned)off) ? sm[threadIdx.x - off] : 0;
        __syncthreads();
        sm[threadIdx.x] += t;
        __syncthreads();
    }
    if (i < n) incl[i] = sm[threadIdx.x];
    if (threadIdx.x == 1023) part[blockIdx.x] = sm[1023];
}

__global__ void scan2(int* __restrict__ part, int nb) {
    int t = threadIdx.x;  // 64
    int v = (t < nb) ? part[t] : 0;
    int orig = v;
    #pragma unroll
    for (int off = 1; off < 64; off <<= 1) {
        int u = __shfl_up(v, off, 64);
        if (t >= off) v += u;
    }
    if (t < nb) part[t] = v - orig;  // exclusive chunk offset
}

__global__ void scan3(const int* __restrict__ indeg, int* __restrict__ rowptr,
                      int* __restrict__ cursor, const int* __restrict__ part,
                      float* __restrict__ dinv, int n, int E) {
    int i = blockIdx.x * blockDim.x + threadIdx.x;
    if (i < n) {
        int excl = rowptr[i] - indeg[i] + part[i >> 10];
        rowptr[i] = excl;
        cursor[i] = excl;
        dinv[i] = rsqrtf((float)indeg[i] + 1.0f);  // +1 self-loop
    }
    if (i == 0) rowptr[n] = E;
}

__global__ void fill_csr(const int* __restrict__ src, const int* __restrict__ dst,
                         int* __restrict__ cursor, int* __restrict__ col, int E) {
    int e = blockIdx.x * blockDim.x + threadIdx.x;
    if (e < E) {
        int p = atomicAdd(&cursor[dst[e]], 1);
        col[p] = src[e];
    }
}

// ---------------- bf16 MFMA GEMM: C[m,n] = dinv[m] * sum_k A[m,k]*Bt[n,k] ----------------
// 128x128 tile, 256 threads = 4 waves (2x2), each wave 4x4 tiles of 16x16x32.
// Double-buffered global_load_lds staging, ONE barrier per 32-wide K-tile:
//   sync (publish tile k) -> issue DMA(k+1) into other buf -> compute tile k.
// The vmcnt(0) drain at the next barrier waits on a DMA that had the whole
// compute phase in flight. K is always a multiple of 64 -> unroll x2.

__device__ __forceinline__ void mfma_step(const ushort* __restrict__ Asb,
                                          const ushort* __restrict__ Bsb,
                                          int arow, int brow, int quad,
                                          float4_t (&acc)[4][4]) {
    short8_t aF[4], bF[4];
    #pragma unroll
    for (int i = 0; i < 4; ++i)
        aF[i] = *(const short8_t*)&Asb[(arow + i * 16) * 32 + quad * 8];
    #pragma unroll
    for (int j = 0; j < 4; ++j)
        bF[j] = *(const short8_t*)&Bsb[(brow + j * 16) * 32 + quad * 8];
    #pragma unroll
    for (int i = 0; i < 4; ++i)
        #pragma unroll
        for (int j = 0; j < 4; ++j)
            acc[i][j] = __builtin_amdgcn_mfma_f32_16x16x32_bf16(aF[i], bF[j], acc[i][j], 0, 0, 0);
}

__global__ __launch_bounds__(256) void gemm_mfma(const ushort* __restrict__ A,
                                                 const ushort* __restrict__ Bt,
                                                 const float* __restrict__ dinv,
                                                 ushort* __restrict__ C,
                                                 int M, int Ncols, int K, int ldc) {
    __shared__ __align__(16) ushort As[2 * 4096];
    __shared__ __align__(16) ushort Bs[2 * 4096];
    int tid = threadIdx.x;
    int lane = tid & 63, w = tid >> 6;
    int wr = w >> 1, wc = w & 1;
    int bm = blockIdx.x * 128, bn = blockIdx.y * 128;

    float4_t acc[4][4];
    #pragma unroll
    for (int i = 0; i < 4; ++i)
        #pragma unroll
        for (int j = 0; j < 4; ++j) acc[i][j] = (float4_t)0.0f;

    // staging addrs: lane covers row (tid>>2), k-chunk (tid&3)*8 (16 B);
    // LDS dest = wave-uniform base + lane*16 == byte offset tid*16 within buf.
    int r0 = tid >> 2;
    int kb = (tid & 3) * 8;
    const ushort* ga0 = A + (size_t)(bm + r0) * K + kb;
    const ushort* ga1 = A + (size_t)(bm + r0 + 64) * K + kb;
    const ushort* gb0 = Bt + (size_t)(bn + r0) * K + kb;
    const ushort* gb1 = Bt + (size_t)(bn + r0 + 64) * K + kb;
    int w512 = w * 512;

#define ISSUE_DMA(kk, bufofs)                              \
    do {                                                   \
        GLDS16(ga0 + (kk), As + (bufofs) + w512);          \
        GLDS16(ga1 + (kk), As + (bufofs) + 2048 + w512);   \
        GLDS16(gb0 + (kk), Bs + (bufofs) + w512);          \
        GLDS16(gb1 + (kk), Bs + (bufofs) + 2048 + w512);   \
    } while (0)

    int arow = wr * 64 + (lane & 15);
    int brow = wc * 64 + (lane & 15);
    int quad = lane >> 4;

    ISSUE_DMA(0, 0);  // prologue -> buf0
    for (int k0 = 0; k0 < K; k0 += 64) {
        __syncthreads();                      // buf0 tile (k0) published
        ISSUE_DMA(k0 + 32, 4096);             // next tile -> buf1 (k0+32 < K always)
        mfma_step(As, Bs, arow, brow, quad, acc);
        __syncthreads();                      // buf1 tile (k0+32) published
        if (k0 + 64 < K) ISSUE_DMA(k0 + 64, 0);
        mfma_step(As + 4096, Bs + 4096, arow, brow, quad, acc);
    }
#undef ISSUE_DMA

    // C/D layout: col = lane&15, row = (lane>>4)*4 + reg
    int colb = bn + wc * 64 + (lane & 15);
    #pragma unroll
    for (int i = 0; i < 4; ++i) {
        int mb = bm + wr * 64 + i * 16 + quad * 4;
        #pragma unroll
        for (int r = 0; r < 4; ++r) {
            int m = mb + r;
            if (m >= M) continue;
            float s = dinv[m];
            #pragma unroll
            for (int j = 0; j < 4; ++j) {
                int n = colb + j * 16;
                if (n < Ncols) C[(size_t)m * ldc + n] = f2bf(acc[i][j][r] * s);
            }
        }
    }
}

// ---------------- aggregation: one wave per node, bf16 in/out ----------------
// Edge ids pre-loaded 64-at-a-time (one coalesced load), shfl-broadcast; gathers
// issue in uniform padded groups of 16 (invalid slots gather row 0, masked by
// fmaf weight) -> 1 latency exposure for deg<=16 (~55% of nodes at avg deg 16).

template <int F, bool RELU>
__global__ __launch_bounds__(256) void agg_bf(const ushort* __restrict__ g,
                                              const int* __restrict__ rowptr,
                                              const int* __restrict__ col,
                                              const float* __restrict__ dinv,
                                              const float* __restrict__ bias,
                                              ushort* __restrict__ out,
                                              int n, int npad) {
    constexpr int VPT = F / 64;
    int wid = (int)((blockIdx.x * blockDim.x + threadIdx.x) >> 6);
    int lane = threadIdx.x & 63;
    if (wid >= npad) return;
    int off = lane * VPT;
    ushort* orow = out + (size_t)wid * F + off;
    if (wid >= n) {  // zero padded tail rows (next GEMM reads them)
        #pragma unroll
        for (int j = 0; j < VPT; ++j) orow[j] = 0;
        return;
    }
    float acc[VPT];
    #pragma unroll
    for (int j = 0; j < VPT; ++j) acc[j] = 0.f;

    int e0 = rowptr[wid];
    int deg = rowptr[wid + 1] - e0;

    for (int base = 0; base < deg; base += 64) {
        int cnt = min(64, deg - base);
        int ec = (lane < cnt) ? col[e0 + base + lane] : 0;  // lanes >= cnt hold 0
        for (int j = 0; j < cnt; j += 16) {
            int s[16];
            #pragma unroll
            for (int u = 0; u < 16; ++u) s[u] = __shfl(ec, j + u);  // pad slots -> row 0
            if constexpr (VPT == 4) {
                ushort4 v[16];
                #pragma unroll
                for (int u = 0; u < 16; ++u)
                    v[u] = *(const ushort4*)(g + (size_t)s[u] * F + off);
                #pragma unroll
                for (int u = 0; u < 16; ++u) {
                    float wv = (j + u < cnt) ? 1.f : 0.f;
                    acc[0] = fmaf(wv, bf2f(v[u].x), acc[0]);
                    acc[1] = fmaf(wv, bf2f(v[u].y), acc[1]);
                    acc[2] = fmaf(wv, bf2f(v[u].z), acc[2]);
                    acc[3] = fmaf(wv, bf2f(v[u].w), acc[3]);
                }
            } else if constexpr (VPT == 2) {
                ushort2 v[16];
                #pragma unroll
                for (int u = 0; u < 16; ++u)
                    v[u] = *(const ushort2*)(g + (size_t)s[u] * F + off);
                #pragma unroll
                for (int u = 0; u < 16; ++u) {
                    float wv = (j + u < cnt) ? 1.f : 0.f;
                    acc[0] = fmaf(wv, bf2f(v[u].x), acc[0]);
                    acc[1] = fmaf(wv, bf2f(v[u].y), acc[1]);
                }
            } else {
                ushort v[16];
                #pragma unroll
                for (int u = 0; u < 16; ++u) v[u] = g[(size_t)s[u] * F + off];
                #pragma unroll
                for (int u = 0; u < 16; ++u) {
                    float wv = (j + u < cnt) ? 1.f : 0.f;
                    acc[0] = fmaf(wv, bf2f(v[u]), acc[0]);
                }
            }
        }
    }

    const ushort* rowi = g + (size_t)wid * F + off;
    float di = dinv[wid];
    #pragma unroll
    for (int j = 0; j < VPT; ++j) {
        float v = di * (acc[j] + bf2f(rowi[j])) + bias[off + j];
        if (RELU) v = fmaxf(v, 0.f);
        orow[j] = f2bf(v);
    }
}

// ---------------- pooling + final linear ----------------

__global__ __launch_bounds__(256) void pool_sorted(const ushort* __restrict__ h,
                                                   const int* __restrict__ batch,
                                                   float* __restrict__ sums,
                                                   float* __restrict__ cnt, int n) {
    int wave = (int)((blockIdx.x * blockDim.x + threadIdx.x) >> 6);
    int lane = threadIdx.x & 63;
    int start = wave * 64;
    if (start >= n) return;
    int end = min(start + 64, n);
    float acc = 0.f;
    int cur = batch[start];
    int runlen = 0;
    for (int i = start; i < end; ++i) {
        int b = batch[i];
        if (b != cur) {
            atomicAdd(&sums[cur * 64 + lane], acc);
            if (lane == 0) atomicAdd(&cnt[cur], (float)runlen);
            acc = 0.f;
            runlen = 0;
            cur = b;
        }
        acc += bf2f(h[(size_t)i * 64 + lane]);
        runlen++;
    }
    atomicAdd(&sums[cur * 64 + lane], acc);
    if (lane == 0) atomicAdd(&cnt[cur], (float)runlen);
}

__global__ void final_lin(const float* __restrict__ sums, const float* __restrict__ cnt,
                          const float* __restrict__ Wl, const float* __restrict__ bl,
                          float* __restrict__ out) {
    int t = threadIdx.x;  // 128 threads: (graph, j)
    int g = t >> 1, j = t & 1;
    float c = fmaxf(cnt[g], 1.0f);
    float a = 0.f;
    #pragma unroll
    for (int k = 0; k < 64; ++k) a += sums[g * 64 + k] * Wl[k * 2 + j];
    out[t] = a / c + bl[j];
}

// ---------------- launch ----------------

extern "C" void kernel_launch(void* const* d_in, const int* in_sizes, int n_in,
                              void* d_out, int out_size, void* d_ws, size_t ws_size,
                              hipStream_t stream) {
    const float* x   = (const float*)d_in[0];
    const int*   ei  = (const int*)d_in[1];
    const int*   bat = (const int*)d_in[2];
    const float* W1  = (const float*)d_in[3];
    const float* b1  = (const float*)d_in[4];
    const float* W2  = (const float*)d_in[5];
    const float* b2  = (const float*)d_in[6];
    const float* W3  = (const float*)d_in[7];
    const float* b3  = (const float*)d_in[8];
    const float* Wl  = (const float*)d_in[9];
    const float* bl  = (const float*)d_in[10];
    float* out = (float*)d_out;

    const int N = in_sizes[0] / 512;
    const int E = in_sizes[1] / 2;
    const int Mpad = ((N + 127) / 128) * 128;   // 50048
    const int* src = ei;
    const int* dst = ei + E;

    char* w = (char*)d_ws;
    auto alloc = [&](size_t bytes) {
        char* p = w;
        w += (bytes + 255) & ~(size_t)255;
        return p;
    };
    ushort* Xb   = (ushort*)alloc((size_t)Mpad * 512 * 2);  // bf16 x (L3-resident)
    ushort* G    = (ushort*)alloc((size_t)Mpad * 256 * 2);  // gemm output
    ushort* H    = (ushort*)alloc((size_t)Mpad * 256 * 2);  // agg output
    ushort* Wt1  = (ushort*)alloc(256 * 512 * 2);
    ushort* Wt2  = (ushort*)alloc(128 * 256 * 2);
    ushort* Wt3  = (ushort*)alloc(128 * 128 * 2);
    float* dinv  = (float*)alloc((size_t)N * 4);
    int* rowptr  = (int*)alloc((size_t)(N + 1) * 4);
    int* cursor  = (int*)alloc((size_t)N * 4);
    int* col     = (int*)alloc((size_t)E * 4);
    int* part    = (int*)alloc(256 * 4);
    size_t zbytes = (size_t)N * 4 + 64 * 64 * 4 + 64 * 4;  // indeg + sums + cnt
    int* indeg   = (int*)alloc(zbytes);
    float* sums  = (float*)(indeg + N);
    float* cnt   = sums + 64 * 64;

    hipMemsetAsync(indeg, 0, zbytes, stream);

    // converts
    conv_x_k<<<(Mpad * 128 + 255) / 256, 256, 0, stream>>>(x, Xb, N, Mpad);
    conv_weights<<<(180224 + 255) / 256, 256, 0, stream>>>(W1, Wt1, W2, Wt2, W3, Wt3);

    // CSR
    count_indeg<<<(E + 255) / 256, 256, 0, stream>>>(dst, indeg, E);
    int nb = (N + 1023) / 1024;
    scan1<<<nb, 1024, 0, stream>>>(indeg, rowptr, part, N);
    scan2<<<1, 64, 0, stream>>>(part, nb);
    scan3<<<(N + 255) / 256, 256, 0, stream>>>(indeg, rowptr, cursor, part, dinv, N, E);
    fill_csr<<<(E + 255) / 256, 256, 0, stream>>>(src, dst, cursor, col, E);

    int npad = Mpad;
    // layer 1: 512 -> 256
    gemm_mfma<<<dim3(Mpad / 128, 2), 256, 0, stream>>>(Xb, Wt1, dinv, G, N, 256, 512, 256);
    agg_bf<256, true><<<npad / 4, 256, 0, stream>>>(G, rowptr, col, dinv, b1, H, N, npad);
    // layer 2: 256 -> 128
    gemm_mfma<<<dim3(Mpad / 128, 1), 256, 0, stream>>>(H, Wt2, dinv, G, N, 128, 256, 128);
    agg_bf<128, true><<<npad / 4, 256, 0, stream>>>(G, rowptr, col, dinv, b2, H, N, npad);
    // layer 3: 128 -> 64 (Wt3 padded to 128 rows, store guarded n<64)
    gemm_mfma<<<dim3(Mpad / 128, 1), 256, 0, stream>>>(H, Wt3, dinv, G, N, 64, 128, 64);
    agg_bf<64, false><<<npad / 4, 256, 0, stream>>>(G, rowptr, col, dinv, b3, H, N, npad);

    pool_sorted<<<(N + 255) / 256, 256, 0, stream>>>(H, bat, sums, cnt, N);
    final_lin<<<1, 128, 0, stream>>>(sums, cnt, Wl, bl, out);
}

// Round 9
// 481.851 us; speedup vs baseline: 1.0247x; 1.0141x over previous
//
#include <hip/hip_runtime.h>
#include <hip/hip_bf16.h>

// GCN: 3x gcn_conv + mean-pool + linear, bf16 MFMA pipeline.
// out[i] = dinv[i] * (sum_{e: dst=i} g[src_e] + g[i]) + b,  g = dinv .* (x @ W)

typedef __attribute__((ext_vector_type(8))) short short8_t;
typedef __attribute__((ext_vector_type(4))) float float4_t;

__device__ __forceinline__ unsigned short f2bf(float f) {
    unsigned int u = __float_as_uint(f);
    u += 0x7FFFu + ((u >> 16) & 1u);   // round-to-nearest-even
    return (unsigned short)(u >> 16);
}
__device__ __forceinline__ float bf2f(unsigned short h) {
    return __uint_as_float(((unsigned int)h) << 16);
}

// async global->LDS, 16B per lane; LDS dest is wave-uniform base + lane*16 (m104/m108)
#define GLDS16(gp, lp)                                                          \
    __builtin_amdgcn_global_load_lds(                                           \
        (const __attribute__((address_space(1))) void*)(gp),                    \
        (__attribute__((address_space(3))) void*)(lp), 16, 0, 0)

// ---------------- converts ----------------

__global__ __launch_bounds__(256) void conv_x_k(const float* __restrict__ x,
                                                ushort* __restrict__ Xb,
                                                int M, int Mpad) {
    int t = blockIdx.x * 256 + threadIdx.x;  // one float4 -> ushort4
    int total = Mpad * 128;                  // 512/4 per row
    if (t >= total) return;
    int row = t >> 7;
    ushort4 o;
    if (row < M) {
        float4 v = ((const float4*)x)[t];
        o.x = f2bf(v.x); o.y = f2bf(v.y); o.z = f2bf(v.z); o.w = f2bf(v.w);
    } else {
        o.x = o.y = o.z = o.w = 0;
    }
    ((ushort4*)Xb)[t] = o;
}

// all three weights, fused: W fp32 [K][N] -> Wt bf16 [Npad][K]
__global__ void conv_weights(const float* __restrict__ W1, ushort* __restrict__ Wt1,
                             const float* __restrict__ W2, ushort* __restrict__ Wt2,
                             const float* __restrict__ W3, ushort* __restrict__ Wt3) {
    int t = blockIdx.x * 256 + threadIdx.x;
    if (t < 131072) {                       // Wt1 [256][512], N=256
        int k = t & 511, n = t >> 9;
        Wt1[t] = f2bf(W1[(size_t)k * 256 + n]);
    } else if (t < 163840) {                // Wt2 [128][256], N=128
        int u = t - 131072;
        int k = u & 255, n = u >> 8;
        Wt2[u] = f2bf(W2[(size_t)k * 128 + n]);
    } else if (t < 180224) {                // Wt3 [128][128], N=64 (rows 64.. zero)
        int u = t - 163840;
        int k = u & 127, n = u >> 7;
        Wt3[u] = (n < 64) ? f2bf(W3[(size_t)k * 64 + n]) : (ushort)0;
    }
}

// ---------------- CSR build ----------------

__global__ void count_indeg(const int* __restrict__ dst, int* __restrict__ indeg, int E) {
    int e = blockIdx.x * blockDim.x + threadIdx.x;
    if (e < E) atomicAdd(&indeg[dst[e]], 1);
}

// hierarchical scan: per-1024-chunk inclusive -> chunk totals -> combine
__global__ __launch_bounds__(1024) void scan1(const int* __restrict__ indeg,
                                              int* __restrict__ incl,   // rowptr as temp
                                              int* __restrict__ part, int n) {
    __shared__ int sm[1024];
    int i = blockIdx.x * 1024 + threadIdx.x;
    int v = (i < n) ? indeg[i] : 0;
    sm[threadIdx.x] = v;
    __syncthreads();
    #pragma unroll
    for (int off = 1; off < 1024; off <<= 1) {
        int t = (threadIdx.x >= (unsigned)off) ? sm[threadIdx.x - off] : 0;
        __syncthreads();
        sm[threadIdx.x] += t;
        __syncthreads();
    }
    if (i < n) incl[i] = sm[threadIdx.x];
    if (threadIdx.x == 1023) part[blockIdx.x] = sm[1023];
}

__global__ void scan2(int* __restrict__ part, int nb) {
    int t = threadIdx.x;  // 64
    int v = (t < nb) ? part[t] : 0;
    int orig = v;
    #pragma unroll
    for (int off = 1; off < 64; off <<= 1) {
        int u = __shfl_up(v, off, 64);
        if (t >= off) v += u;
    }
    if (t < nb) part[t] = v - orig;  // exclusive chunk offset
}

// also zeroes dinv for pad rows [n, npad)
__global__ void scan3(const int* __restrict__ indeg, int* __restrict__ rowptr,
                      int* __restrict__ cursor, const int* __restrict__ part,
                      float* __restrict__ dinv, int n, int npad, int E) {
    int i = blockIdx.x * blockDim.x + threadIdx.x;
    if (i < n) {
        int excl = rowptr[i] - indeg[i] + part[i >> 10];
        rowptr[i] = excl;
        cursor[i] = excl;
        dinv[i] = rsqrtf((float)indeg[i] + 1.0f);  // +1 self-loop
    } else if (i < npad) {
        dinv[i] = 0.f;                             // pad rows -> C rows are exact 0
    }
    if (i == 0) rowptr[n] = E;
}

__global__ void fill_csr(const int* __restrict__ src, const int* __restrict__ dst,
                         int* __restrict__ cursor, int* __restrict__ col, int E) {
    int e = blockIdx.x * blockDim.x + threadIdx.x;
    if (e < E) {
        int p = atomicAdd(&cursor[dst[e]], 1);
        col[p] = src[e];
    }
}

// ---------------- bf16 MFMA GEMM: C[m,n] = dinv[m] * sum_k A[m,k]*Bt[n,k] ----------------
// 128x128 tile, 256 threads = 4 waves (2x2), each wave 4x4 tiles of 16x16x32.
// Double-buffered global_load_lds staging. Stores ALL Mpad rows (pad rows have
// A=0, dinv=0 -> exact zeros) so row N is a valid zero-gather target for agg.

__device__ __forceinline__ void mfma_step(const ushort* __restrict__ Asb,
                                          const ushort* __restrict__ Bsb,
                                          int arow, int brow, int quad,
                                          float4_t (&acc)[4][4]) {
    short8_t aF[4], bF[4];
    #pragma unroll
    for (int i = 0; i < 4; ++i)
        aF[i] = *(const short8_t*)&Asb[(arow + i * 16) * 32 + quad * 8];
    #pragma unroll
    for (int j = 0; j < 4; ++j)
        bF[j] = *(const short8_t*)&Bsb[(brow + j * 16) * 32 + quad * 8];
    #pragma unroll
    for (int i = 0; i < 4; ++i)
        #pragma unroll
        for (int j = 0; j < 4; ++j)
            acc[i][j] = __builtin_amdgcn_mfma_f32_16x16x32_bf16(aF[i], bF[j], acc[i][j], 0, 0, 0);
}

__global__ __launch_bounds__(256) void gemm_mfma(const ushort* __restrict__ A,
                                                 const ushort* __restrict__ Bt,
                                                 const float* __restrict__ dinv,
                                                 ushort* __restrict__ C,
                                                 int Ncols, int K, int ldc) {
    __shared__ __align__(16) ushort As[2 * 4096];
    __shared__ __align__(16) ushort Bs[2 * 4096];
    int tid = threadIdx.x;
    int lane = tid & 63, w = tid >> 6;
    int wr = w >> 1, wc = w & 1;
    int bm = blockIdx.x * 128, bn = blockIdx.y * 128;

    float4_t acc[4][4];
    #pragma unroll
    for (int i = 0; i < 4; ++i)
        #pragma unroll
        for (int j = 0; j < 4; ++j) acc[i][j] = (float4_t)0.0f;

    int r0 = tid >> 2;
    int kb = (tid & 3) * 8;
    const ushort* ga0 = A + (size_t)(bm + r0) * K + kb;
    const ushort* ga1 = A + (size_t)(bm + r0 + 64) * K + kb;
    const ushort* gb0 = Bt + (size_t)(bn + r0) * K + kb;
    const ushort* gb1 = Bt + (size_t)(bn + r0 + 64) * K + kb;
    int w512 = w * 512;

#define ISSUE_DMA(kk, bufofs)                              \
    do {                                                   \
        GLDS16(ga0 + (kk), As + (bufofs) + w512);          \
        GLDS16(ga1 + (kk), As + (bufofs) + 2048 + w512);   \
        GLDS16(gb0 + (kk), Bs + (bufofs) + w512);          \
        GLDS16(gb1 + (kk), Bs + (bufofs) + 2048 + w512);   \
    } while (0)

    int arow = wr * 64 + (lane & 15);
    int brow = wc * 64 + (lane & 15);
    int quad = lane >> 4;

    ISSUE_DMA(0, 0);  // prologue -> buf0
    for (int k0 = 0; k0 < K; k0 += 64) {
        __syncthreads();                      // buf0 tile (k0) published
        ISSUE_DMA(k0 + 32, 4096);             // next tile -> buf1 (k0+32 < K always)
        mfma_step(As, Bs, arow, brow, quad, acc);
        __syncthreads();                      // buf1 tile (k0+32) published
        if (k0 + 64 < K) ISSUE_DMA(k0 + 64, 0);
        mfma_step(As + 4096, Bs + 4096, arow, brow, quad, acc);
    }
#undef ISSUE_DMA

    // C/D layout: col = lane&15, row = (lane>>4)*4 + reg
    int colb = bn + wc * 64 + (lane & 15);
    #pragma unroll
    for (int i = 0; i < 4; ++i) {
        int mb = bm + wr * 64 + i * 16 + quad * 4;
        #pragma unroll
        for (int r = 0; r < 4; ++r) {
            int m = mb + r;
            float s = dinv[m];
            #pragma unroll
            for (int j = 0; j < 4; ++j) {
                int n = colb + j * 16;
                if (n < Ncols) C[(size_t)m * ldc + n] = f2bf(acc[i][j][r] * s);
            }
        }
    }
}

// ---------------- aggregation: one wave per node, bf16 in/out ----------------
// R6-proven structure: per-lane VECTOR col loads (coherent across dispatches),
// __shfl broadcast, 16-deep gather groups. Pad slots load the guaranteed-zero
// row zrow (lanes >= cnt hold ec=zrow) and accumulate unconditionally -> no
// per-element masks. NO scalar/s_load edge reads (R7's post-timing divergence).

template <int F, bool RELU>
__global__ __launch_bounds__(256) void agg_bf(const ushort* __restrict__ g,
                                              const int* __restrict__ rowptr,
                                              const int* __restrict__ col,
                                              const float* __restrict__ dinv,
                                              const float* __restrict__ bias,
                                              ushort* __restrict__ out,
                                              int n, int npad, int zrow) {
    constexpr int VPT = F / 64;
    int wid = (int)((blockIdx.x * blockDim.x + threadIdx.x) >> 6);
    int lane = threadIdx.x & 63;
    if (wid >= npad) return;
    int off = lane * VPT;
    ushort* orow = out + (size_t)wid * F + off;
    if (wid >= n) {  // zero padded tail rows (zero-gather targets + next GEMM A)
        #pragma unroll
        for (int j = 0; j < VPT; ++j) orow[j] = 0;
        return;
    }

    // self row: issue early (independent of the gather stream)
    const ushort* rowi = g + (size_t)wid * F + off;
    float self[VPT];
    if constexpr (VPT == 4) {
        ushort4 sv = *(const ushort4*)rowi;
        self[0] = bf2f(sv.x); self[1] = bf2f(sv.y);
        self[2] = bf2f(sv.z); self[3] = bf2f(sv.w);
    } else if constexpr (VPT == 2) {
        ushort2 sv = *(const ushort2*)rowi;
        self[0] = bf2f(sv.x); self[1] = bf2f(sv.y);
    } else {
        self[0] = bf2f(rowi[0]);
    }

    float acc[VPT];
    #pragma unroll
    for (int j = 0; j < VPT; ++j) acc[j] = 0.f;

    int e0 = rowptr[wid];
    int deg = rowptr[wid + 1] - e0;

    for (int base = 0; base < deg; base += 64) {
        int cnt = min(64, deg - base);
        int ec = (lane < cnt) ? col[e0 + base + lane] : zrow;  // pad lanes -> zero row
        for (int j = 0; j < cnt; j += 16) {
            int s[16];
            #pragma unroll
            for (int u = 0; u < 16; ++u) s[u] = __shfl(ec, j + u);  // j+u<64; pad->zrow
            if constexpr (VPT == 4) {
                ushort4 v[16];
                #pragma unroll
                for (int u = 0; u < 16; ++u)
                    v[u] = *(const ushort4*)(g + (size_t)s[u] * F + off);
                #pragma unroll
                for (int u = 0; u < 16; ++u) {
                    acc[0] += bf2f(v[u].x); acc[1] += bf2f(v[u].y);
                    acc[2] += bf2f(v[u].z); acc[3] += bf2f(v[u].w);
                }
            } else if constexpr (VPT == 2) {
                ushort2 v[16];
                #pragma unroll
                for (int u = 0; u < 16; ++u)
                    v[u] = *(const ushort2*)(g + (size_t)s[u] * F + off);
                #pragma unroll
                for (int u = 0; u < 16; ++u) {
                    acc[0] += bf2f(v[u].x); acc[1] += bf2f(v[u].y);
                }
            } else {
                ushort v[16];
                #pragma unroll
                for (int u = 0; u < 16; ++u) v[u] = g[(size_t)s[u] * F + off];
                #pragma unroll
                for (int u = 0; u < 16; ++u) acc[0] += bf2f(v[u]);
            }
        }
    }

    float di = dinv[wid];
    #pragma unroll
    for (int j = 0; j < VPT; ++j) {
        float v = di * (acc[j] + self[j]) + bias[off + j];
        if (RELU) v = fmaxf(v, 0.f);
        orow[j] = f2bf(v);
    }
}

// ---------------- pooling + final linear ----------------

__global__ __launch_bounds__(256) void pool_sorted(const ushort* __restrict__ h,
                                                   const int* __restrict__ batch,
                                                   float* __restrict__ sums,
                                                   float* __restrict__ cnt, int n) {
    int wave = (int)((blockIdx.x * blockDim.x + threadIdx.x) >> 6);
    int lane = threadIdx.x & 63;
    int start = wave * 64;
    if (start >= n) return;
    int end = min(start + 64, n);
    float acc = 0.f;
    int cur = batch[start];
    int runlen = 0;
    for (int i = start; i < end; ++i) {
        int b = batch[i];
        if (b != cur) {
            atomicAdd(&sums[cur * 64 + lane], acc);
            if (lane == 0) atomicAdd(&cnt[cur], (float)runlen);
            acc = 0.f;
            runlen = 0;
            cur = b;
        }
        acc += bf2f(h[(size_t)i * 64 + lane]);
        runlen++;
    }
    atomicAdd(&sums[cur * 64 + lane], acc);
    if (lane == 0) atomicAdd(&cnt[cur], (float)runlen);
}

__global__ void final_lin(const float* __restrict__ sums, const float* __restrict__ cnt,
                          const float* __restrict__ Wl, const float* __restrict__ bl,
                          float* __restrict__ out) {
    int t = threadIdx.x;  // 128 threads: (graph, j)
    int g = t >> 1, j = t & 1;
    float c = fmaxf(cnt[g], 1.0f);
    float a = 0.f;
    #pragma unroll
    for (int k = 0; k < 64; ++k) a += sums[g * 64 + k] * Wl[k * 2 + j];
    out[t] = a / c + bl[j];
}

// ---------------- launch ----------------

extern "C" void kernel_launch(void* const* d_in, const int* in_sizes, int n_in,
                              void* d_out, int out_size, void* d_ws, size_t ws_size,
                              hipStream_t stream) {
    const float* x   = (const float*)d_in[0];
    const int*   ei  = (const int*)d_in[1];
    const int*   bat = (const int*)d_in[2];
    const float* W1  = (const float*)d_in[3];
    const float* b1  = (const float*)d_in[4];
    const float* W2  = (const float*)d_in[5];
    const float* b2  = (const float*)d_in[6];
    const float* W3  = (const float*)d_in[7];
    const float* b3  = (const float*)d_in[8];
    const float* Wl  = (const float*)d_in[9];
    const float* bl  = (const float*)d_in[10];
    float* out = (float*)d_out;

    const int N = in_sizes[0] / 512;
    const int E = in_sizes[1] / 2;
    const int Mpad = ((N + 127) / 128) * 128;   // 50048
    const int* src = ei;
    const int* dst = ei + E;

    char* w = (char*)d_ws;
    auto alloc = [&](size_t bytes) {
        char* p = w;
        w += (bytes + 255) & ~(size_t)255;
        return p;
    };
    ushort* Xb   = (ushort*)alloc((size_t)Mpad * 512 * 2);  // bf16 x (L3-resident)
    ushort* G    = (ushort*)alloc((size_t)Mpad * 256 * 2);  // gemm output
    ushort* H    = (ushort*)alloc((size_t)Mpad * 256 * 2);  // agg output
    ushort* Wt1  = (ushort*)alloc(256 * 512 * 2);
    ushort* Wt2  = (ushort*)alloc(128 * 256 * 2);
    ushort* Wt3  = (ushort*)alloc(128 * 128 * 2);
    float* dinv  = (float*)alloc((size_t)Mpad * 4);
    int* rowptr  = (int*)alloc((size_t)(N + 1) * 4);
    int* cursor  = (int*)alloc((size_t)N * 4);
    int* col     = (int*)alloc((size_t)(E + 16) * 4);
    int* part    = (int*)alloc(256 * 4);
    size_t zbytes = (size_t)N * 4 + 64 * 64 * 4 + 64 * 4;  // indeg + sums + cnt
    int* indeg   = (int*)alloc(zbytes);
    float* sums  = (float*)(indeg + N);
    float* cnt   = sums + 64 * 64;

    hipMemsetAsync(indeg, 0, zbytes, stream);

    // converts
    conv_x_k<<<(Mpad * 128 + 255) / 256, 256, 0, stream>>>(x, Xb, N, Mpad);
    conv_weights<<<(180224 + 255) / 256, 256, 0, stream>>>(W1, Wt1, W2, Wt2, W3, Wt3);

    // CSR
    count_indeg<<<(E + 255) / 256, 256, 0, stream>>>(dst, indeg, E);
    int nb = (N + 1023) / 1024;
    scan1<<<nb, 1024, 0, stream>>>(indeg, rowptr, part, N);
    scan2<<<1, 64, 0, stream>>>(part, nb);
    scan3<<<(Mpad + 255) / 256, 256, 0, stream>>>(indeg, rowptr, cursor, part, dinv, N, Mpad, E);
    fill_csr<<<(E + 255) / 256, 256, 0, stream>>>(src, dst, cursor, col, E);

    int npad = Mpad;
    // layer 1: 512 -> 256
    gemm_mfma<<<dim3(Mpad / 128, 2), 256, 0, stream>>>(Xb, Wt1, dinv, G, 256, 512, 256);
    agg_bf<256, true><<<npad / 4, 256, 0, stream>>>(G, rowptr, col, dinv, b1, H, N, npad, N);
    // layer 2: 256 -> 128
    gemm_mfma<<<dim3(Mpad / 128, 1), 256, 0, stream>>>(H, Wt2, dinv, G, 128, 256, 128);
    agg_bf<128, true><<<npad / 4, 256, 0, stream>>>(G, rowptr, col, dinv, b2, H, N, npad, N);
    // layer 3: 128 -> 64 (Wt3 padded to 128 rows, store guarded n<64)
    gemm_mfma<<<dim3(Mpad / 128, 1), 256, 0, stream>>>(H, Wt3, dinv, G, 64, 128, 64);
    agg_bf<64, false><<<npad / 4, 256, 0, stream>>>(G, rowptr, col, dinv, b3, H, N, npad, N);

    pool_sorted<<<(N + 255) / 256, 256, 0, stream>>>(H, bat, sums, cnt, N);
    final_lin<<<1, 128, 0, stream>>>(sums, cnt, Wl, bl, out);
}

// Round 10
// 479.123 us; speedup vs baseline: 1.0306x; 1.0057x over previous
//
#include <hip/hip_runtime.h>
#include <hip/hip_bf16.h>

// GCN: 3x gcn_conv + mean-pool + linear, bf16 MFMA pipeline.
// out[i] = dinv[i] * (sum_{e: dst=i} g[src_e] + g[i]) + b,  g = dinv .* (x @ W)

typedef __attribute__((ext_vector_type(8))) short short8_t;
typedef __attribute__((ext_vector_type(4))) float float4_t;

__device__ __forceinline__ unsigned short f2bf(float f) {
    unsigned int u = __float_as_uint(f);
    u += 0x7FFFu + ((u >> 16) & 1u);   // round-to-nearest-even
    return (unsigned short)(u >> 16);
}
__device__ __forceinline__ float bf2f(unsigned short h) {
    return __uint_as_float(((unsigned int)h) << 16);
}

// async global->LDS, 16B per lane; LDS dest is wave-uniform base + lane*16 (m104/m108)
#define GLDS16(gp, lp)                                                          \
    __builtin_amdgcn_global_load_lds(                                           \
        (const __attribute__((address_space(1))) void*)(gp),                    \
        (__attribute__((address_space(3))) void*)(lp), 16, 0, 0)

// ---------------- converts ----------------

__global__ __launch_bounds__(256) void conv_x_k(const float* __restrict__ x,
                                                ushort* __restrict__ Xb,
                                                int M, int Mpad) {
    int t = blockIdx.x * 256 + threadIdx.x;  // one float4 -> ushort4
    int total = Mpad * 128;                  // 512/4 per row
    if (t >= total) return;
    int row = t >> 7;
    ushort4 o;
    if (row < M) {
        float4 v = ((const float4*)x)[t];
        o.x = f2bf(v.x); o.y = f2bf(v.y); o.z = f2bf(v.z); o.w = f2bf(v.w);
    } else {
        o.x = o.y = o.z = o.w = 0;
    }
    ((ushort4*)Xb)[t] = o;
}

// all three weights, fused: W fp32 [K][N] -> Wt bf16 [Npad][K]
__global__ void conv_weights(const float* __restrict__ W1, ushort* __restrict__ Wt1,
                             const float* __restrict__ W2, ushort* __restrict__ Wt2,
                             const float* __restrict__ W3, ushort* __restrict__ Wt3) {
    int t = blockIdx.x * 256 + threadIdx.x;
    if (t < 131072) {                       // Wt1 [256][512], N=256
        int k = t & 511, n = t >> 9;
        Wt1[t] = f2bf(W1[(size_t)k * 256 + n]);
    } else if (t < 163840) {                // Wt2 [128][256], N=128
        int u = t - 131072;
        int k = u & 255, n = u >> 8;
        Wt2[u] = f2bf(W2[(size_t)k * 128 + n]);
    } else if (t < 180224) {                // Wt3 [128][128], N=64 (rows 64.. zero)
        int u = t - 163840;
        int k = u & 127, n = u >> 7;
        Wt3[u] = (n < 64) ? f2bf(W3[(size_t)k * 64 + n]) : (ushort)0;
    }
}

// ---------------- CSR build ----------------

__global__ void count_indeg(const int* __restrict__ dst, int* __restrict__ indeg, int E) {
    int e = blockIdx.x * blockDim.x + threadIdx.x;
    if (e < E) atomicAdd(&indeg[dst[e]], 1);
}

// hierarchical scan: per-1024-chunk inclusive -> chunk totals -> combine
__global__ __launch_bounds__(1024) void scan1(const int* __restrict__ indeg,
                                              int* __restrict__ incl,   // rowptr as temp
                                              int* __restrict__ part, int n) {
    __shared__ int sm[1024];
    int i = blockIdx.x * 1024 + threadIdx.x;
    int v = (i < n) ? indeg[i] : 0;
    sm[threadIdx.x] = v;
    __syncthreads();
    #pragma unroll
    for (int off = 1; off < 1024; off <<= 1) {
        int t = (threadIdx.x >= (unsigned)off) ? sm[threadIdx.x - off] : 0;
        __syncthreads();
        sm[threadIdx.x] += t;
        __syncthreads();
    }
    if (i < n) incl[i] = sm[threadIdx.x];
    if (threadIdx.x == 1023) part[blockIdx.x] = sm[1023];
}

__global__ void scan2(int* __restrict__ part, int nb) {
    int t = threadIdx.x;  // 64
    int v = (t < nb) ? part[t] : 0;
    int orig = v;
    #pragma unroll
    for (int off = 1; off < 64; off <<= 1) {
        int u = __shfl_up(v, off, 64);
        if (t >= off) v += u;
    }
    if (t < nb) part[t] = v - orig;  // exclusive chunk offset
}

// also zeroes dinv for pad rows [n, npad)
__global__ void scan3(const int* __restrict__ indeg, int* __restrict__ rowptr,
                      int* __restrict__ cursor, const int* __restrict__ part,
                      float* __restrict__ dinv, int n, int npad, int E) {
    int i = blockIdx.x * blockDim.x + threadIdx.x;
    if (i < n) {
        int excl = rowptr[i] - indeg[i] + part[i >> 10];
        rowptr[i] = excl;
        cursor[i] = excl;
        dinv[i] = rsqrtf((float)indeg[i] + 1.0f);  // +1 self-loop
    } else if (i < npad) {
        dinv[i] = 0.f;                             // pad rows -> C rows are exact 0
    }
    if (i == 0) rowptr[n] = E;
}

__global__ void fill_csr(const int* __restrict__ src, const int* __restrict__ dst,
                         int* __restrict__ cursor, int* __restrict__ col, int E) {
    int e = blockIdx.x * blockDim.x + threadIdx.x;
    if (e < E) {
        int p = atomicAdd(&cursor[dst[e]], 1);
        col[p] = src[e];
    }
}

// ---------------- bf16 MFMA GEMM: C[m,n] = dinv[m] * sum_k A[m,k]*Bt[n,k] ----------------
// 128x128 tile, 256 threads = 4 waves (2x2), each wave 4x4 tiles of 16x16x32.
// Double-buffered global_load_lds staging. Stores ALL Mpad rows (pad rows have
// A=0, dinv=0 -> exact zeros) so row N is a valid zero-gather target for agg.

__device__ __forceinline__ void mfma_step(const ushort* __restrict__ Asb,
                                          const ushort* __restrict__ Bsb,
                                          int arow, int brow, int quad,
                                          float4_t (&acc)[4][4]) {
    short8_t aF[4], bF[4];
    #pragma unroll
    for (int i = 0; i < 4; ++i)
        aF[i] = *(const short8_t*)&Asb[(arow + i * 16) * 32 + quad * 8];
    #pragma unroll
    for (int j = 0; j < 4; ++j)
        bF[j] = *(const short8_t*)&Bsb[(brow + j * 16) * 32 + quad * 8];
    #pragma unroll
    for (int i = 0; i < 4; ++i)
        #pragma unroll
        for (int j = 0; j < 4; ++j)
            acc[i][j] = __builtin_amdgcn_mfma_f32_16x16x32_bf16(aF[i], bF[j], acc[i][j], 0, 0, 0);
}

__global__ __launch_bounds__(256) void gemm_mfma(const ushort* __restrict__ A,
                                                 const ushort* __restrict__ Bt,
                                                 const float* __restrict__ dinv,
                                                 ushort* __restrict__ C,
                                                 int Ncols, int K, int ldc) {
    __shared__ __align__(16) ushort As[2 * 4096];
    __shared__ __align__(16) ushort Bs[2 * 4096];
    int tid = threadIdx.x;
    int lane = tid & 63, w = tid >> 6;
    int wr = w >> 1, wc = w & 1;
    int bm = blockIdx.x * 128, bn = blockIdx.y * 128;

    float4_t acc[4][4];
    #pragma unroll
    for (int i = 0; i < 4; ++i)
        #pragma unroll
        for (int j = 0; j < 4; ++j) acc[i][j] = (float4_t)0.0f;

    int r0 = tid >> 2;
    int kb = (tid & 3) * 8;
    const ushort* ga0 = A + (size_t)(bm + r0) * K + kb;
    const ushort* ga1 = A + (size_t)(bm + r0 + 64) * K + kb;
    const ushort* gb0 = Bt + (size_t)(bn + r0) * K + kb;
    const ushort* gb1 = Bt + (size_t)(bn + r0 + 64) * K + kb;
    int w512 = w * 512;

#define ISSUE_DMA(kk, bufofs)                              \
    do {                                                   \
        GLDS16(ga0 + (kk), As + (bufofs) + w512);          \
        GLDS16(ga1 + (kk), As + (bufofs) + 2048 + w512);   \
        GLDS16(gb0 + (kk), Bs + (bufofs) + w512);          \
        GLDS16(gb1 + (kk), Bs + (bufofs) + 2048 + w512);   \
    } while (0)

    int arow = wr * 64 + (lane & 15);
    int brow = wc * 64 + (lane & 15);
    int quad = lane >> 4;

    ISSUE_DMA(0, 0);  // prologue -> buf0
    for (int k0 = 0; k0 < K; k0 += 64) {
        __syncthreads();                      // buf0 tile (k0) published
        ISSUE_DMA(k0 + 32, 4096);             // next tile -> buf1 (k0+32 < K always)
        mfma_step(As, Bs, arow, brow, quad, acc);
        __syncthreads();                      // buf1 tile (k0+32) published
        if (k0 + 64 < K) ISSUE_DMA(k0 + 64, 0);
        mfma_step(As + 4096, Bs + 4096, arow, brow, quad, acc);
    }
#undef ISSUE_DMA

    // C/D layout: col = lane&15, row = (lane>>4)*4 + reg
    int colb = bn + wc * 64 + (lane & 15);
    #pragma unroll
    for (int i = 0; i < 4; ++i) {
        int mb = bm + wr * 64 + i * 16 + quad * 4;
        #pragma unroll
        for (int r = 0; r < 4; ++r) {
            int m = mb + r;
            float s = dinv[m];
            #pragma unroll
            for (int j = 0; j < 4; ++j) {
                int n = colb + j * 16;
                if (n < Ncols) C[(size_t)m * ldc + n] = f2bf(acc[i][j][r] * s);
            }
        }
    }
}

// ---------------- aggregation: edge-packed, bf16 in/out ----------------
// One wave per node, but EPL edges share each load instruction (half-wave for
// F=256/128: 2 edges @ 1KiB/512B per instr; quarter-wave for F=64: 4 edges @
// 512B). Edge ids: R9-proven coalesced per-lane col vector load + bpermute
// (per-lane source j+u*EPL+h); pad lanes hold zrow (guaranteed-zero row) so
// no masks anywhere. Cross-half shfl_xor folds partials once per node.

template <int DW> struct VecT;
template <> struct VecT<2> { using type = uint2; };
template <> struct VecT<4> { using type = uint4; };

template <int F, bool RELU>
__global__ __launch_bounds__(256) void agg_bf(const ushort* __restrict__ g,
                                              const int* __restrict__ rowptr,
                                              const int* __restrict__ col,
                                              const float* __restrict__ dinv,
                                              const float* __restrict__ bias,
                                              ushort* __restrict__ out,
                                              int n, int npad, int zrow) {
    constexpr int EPL  = (F == 64) ? 4 : 2;  // edges per load instruction
    constexpr int SUBW = 64 / EPL;           // lanes per edge
    constexpr int EPT  = F / SUBW;           // elements per lane (8 for F=256, else 4)
    constexpr int LPG  = 16 / EPL;           // loads per 16-edge flight group
    constexpr int DW   = EPT / 2;            // dwords per load
    using vec_t = typename VecT<DW>::type;

    int wid = (int)((blockIdx.x * blockDim.x + threadIdx.x) >> 6);
    int lane = threadIdx.x & 63;
    if (wid >= npad) return;
    int h   = lane / SUBW;                   // edge slot within a load (0..EPL-1)
    int sub = lane & (SUBW - 1);
    int off = sub * EPT;
    ushort* orow = out + (size_t)wid * F + off;

    if (wid >= n) {  // zero padded tail rows (zero-gather targets + next GEMM A)
        if (h == 0) {
            #pragma unroll
            for (int d = 0; d < DW; ++d) ((uint*)orow)[d] = 0;
        }
        return;
    }

    // self row: issue early; identical across h-slots (same addresses)
    const ushort* gofs = g + off;
    vec_t sv = *(const vec_t*)(gofs + (size_t)wid * F);
    float self[EPT];
    #pragma unroll
    for (int d = 0; d < DW; ++d) {
        uint dw = ((const uint*)&sv)[d];
        self[2 * d]     = __uint_as_float(dw << 16);
        self[2 * d + 1] = __uint_as_float(dw & 0xffff0000u);
    }

    float acc[EPT];
    #pragma unroll
    for (int t = 0; t < EPT; ++t) acc[t] = 0.f;

    int e0 = rowptr[wid];
    int deg = rowptr[wid + 1] - e0;

    for (int base = 0; base < deg; base += 64) {
        int cnt = min(64, deg - base);
        int ec = (lane < cnt) ? col[e0 + base + lane] : zrow;  // pad lanes -> zero row
        for (int j = 0; j < cnt; j += 16) {
            vec_t v[LPG];
            #pragma unroll
            for (int u = 0; u < LPG; ++u) {
                int id = __shfl(ec, j + u * EPL + h);          // <=j+15<64; pad->zrow
                v[u] = *(const vec_t*)(gofs + (size_t)id * F);
            }
            #pragma unroll
            for (int u = 0; u < LPG; ++u)
                #pragma unroll
                for (int d = 0; d < DW; ++d) {
                    uint dw = ((const uint*)&v[u])[d];
                    acc[2 * d]     += __uint_as_float(dw << 16);
                    acc[2 * d + 1] += __uint_as_float(dw & 0xffff0000u);
                }
        }
    }

    // fold edge slots: lanes differing only in h hold the same features
    #pragma unroll
    for (int t = 0; t < EPT; ++t) {
        if constexpr (EPL == 4) acc[t] += __shfl_xor(acc[t], 16, 64);
        acc[t] += __shfl_xor(acc[t], 32, 64);
    }

    float di = dinv[wid];
    ushort res[EPT];
    #pragma unroll
    for (int t = 0; t < EPT; ++t) {
        float r = di * (acc[t] + self[t]) + bias[off + t];
        if (RELU) r = fmaxf(r, 0.f);
        res[t] = f2bf(r);
    }
    if (h == 0) {
        #pragma unroll
        for (int d = 0; d < DW; ++d)
            ((uint*)orow)[d] = (uint)res[2 * d] | ((uint)res[2 * d + 1] << 16);
    }
}

// ---------------- pooling + final linear ----------------

__global__ __launch_bounds__(256) void pool_sorted(const ushort* __restrict__ h,
                                                   const int* __restrict__ batch,
                                                   float* __restrict__ sums,
                                                   float* __restrict__ cnt, int n) {
    int wave = (int)((blockIdx.x * blockDim.x + threadIdx.x) >> 6);
    int lane = threadIdx.x & 63;
    int start = wave * 64;
    if (start >= n) return;
    int end = min(start + 64, n);
    float acc = 0.f;
    int cur = batch[start];
    int runlen = 0;
    for (int i = start; i < end; ++i) {
        int b = batch[i];
        if (b != cur) {
            atomicAdd(&sums[cur * 64 + lane], acc);
            if (lane == 0) atomicAdd(&cnt[cur], (float)runlen);
            acc = 0.f;
            runlen = 0;
            cur = b;
        }
        acc += bf2f(h[(size_t)i * 64 + lane]);
        runlen++;
    }
    atomicAdd(&sums[cur * 64 + lane], acc);
    if (lane == 0) atomicAdd(&cnt[cur], (float)runlen);
}

__global__ void final_lin(const float* __restrict__ sums, const float* __restrict__ cnt,
                          const float* __restrict__ Wl, const float* __restrict__ bl,
                          float* __restrict__ out) {
    int t = threadIdx.x;  // 128 threads: (graph, j)
    int g = t >> 1, j = t & 1;
    float c = fmaxf(cnt[g], 1.0f);
    float a = 0.f;
    #pragma unroll
    for (int k = 0; k < 64; ++k) a += sums[g * 64 + k] * Wl[k * 2 + j];
    out[t] = a / c + bl[j];
}

// ---------------- launch ----------------

extern "C" void kernel_launch(void* const* d_in, const int* in_sizes, int n_in,
                              void* d_out, int out_size, void* d_ws, size_t ws_size,
                              hipStream_t stream) {
    const float* x   = (const float*)d_in[0];
    const int*   ei  = (const int*)d_in[1];
    const int*   bat = (const int*)d_in[2];
    const float* W1  = (const float*)d_in[3];
    const float* b1  = (const float*)d_in[4];
    const float* W2  = (const float*)d_in[5];
    const float* b2  = (const float*)d_in[6];
    const float* W3  = (const float*)d_in[7];
    const float* b3  = (const float*)d_in[8];
    const float* Wl  = (const float*)d_in[9];
    const float* bl  = (const float*)d_in[10];
    float* out = (float*)d_out;

    const int N = in_sizes[0] / 512;
    const int E = in_sizes[1] / 2;
    const int Mpad = ((N + 127) / 128) * 128;   // 50048
    const int* src = ei;
    const int* dst = ei + E;

    char* w = (char*)d_ws;
    auto alloc = [&](size_t bytes) {
        char* p = w;
        w += (bytes + 255) & ~(size_t)255;
        return p;
    };
    ushort* Xb   = (ushort*)alloc((size_t)Mpad * 512 * 2);  // bf16 x (L3-resident)
    ushort* G    = (ushort*)alloc((size_t)Mpad * 256 * 2);  // gemm output
    ushort* H    = (ushort*)alloc((size_t)Mpad * 256 * 2);  // agg output
    ushort* Wt1  = (ushort*)alloc(256 * 512 * 2);
    ushort* Wt2  = (ushort*)alloc(128 * 256 * 2);
    ushort* Wt3  = (ushort*)alloc(128 * 128 * 2);
    float* dinv  = (float*)alloc((size_t)Mpad * 4);
    int* rowptr  = (int*)alloc((size_t)(N + 1) * 4);
    int* cursor  = (int*)alloc((size_t)N * 4);
    int* col     = (int*)alloc((size_t)(E + 16) * 4);
    int* part    = (int*)alloc(256 * 4);
    size_t zbytes = (size_t)N * 4 + 64 * 64 * 4 + 64 * 4;  // indeg + sums + cnt
    int* indeg   = (int*)alloc(zbytes);
    float* sums  = (float*)(indeg + N);
    float* cnt   = sums + 64 * 64;

    hipMemsetAsync(indeg, 0, zbytes, stream);

    // converts
    conv_x_k<<<(Mpad * 128 + 255) / 256, 256, 0, stream>>>(x, Xb, N, Mpad);
    conv_weights<<<(180224 + 255) / 256, 256, 0, stream>>>(W1, Wt1, W2, Wt2, W3, Wt3);

    // CSR
    count_indeg<<<(E + 255) / 256, 256, 0, stream>>>(dst, indeg, E);
    int nb = (N + 1023) / 1024;
    scan1<<<nb, 1024, 0, stream>>>(indeg, rowptr, part, N);
    scan2<<<1, 64, 0, stream>>>(part, nb);
    scan3<<<(Mpad + 255) / 256, 256, 0, stream>>>(indeg, rowptr, cursor, part, dinv, N, Mpad, E);
    fill_csr<<<(E + 255) / 256, 256, 0, stream>>>(src, dst, cursor, col, E);

    int npad = Mpad;
    // layer 1: 512 -> 256
    gemm_mfma<<<dim3(Mpad / 128, 2), 256, 0, stream>>>(Xb, Wt1, dinv, G, 256, 512, 256);
    agg_bf<256, true><<<npad / 4, 256, 0, stream>>>(G, rowptr, col, dinv, b1, H, N, npad, N);
    // layer 2: 256 -> 128
    gemm_mfma<<<dim3(Mpad / 128, 1), 256, 0, stream>>>(H, Wt2, dinv, G, 128, 256, 128);
    agg_bf<128, true><<<npad / 4, 256, 0, stream>>>(G, rowptr, col, dinv, b2, H, N, npad, N);
    // layer 3: 128 -> 64 (Wt3 padded to 128 rows, store guarded n<64)
    gemm_mfma<<<dim3(Mpad / 128, 1), 256, 0, stream>>>(H, Wt3, dinv, G, 64, 128, 64);
    agg_bf<64, false><<<npad / 4, 256, 0, stream>>>(G, rowptr, col, dinv, b3, H, N, npad, N);

    pool_sorted<<<(N + 255) / 256, 256, 0, stream>>>(H, bat, sums, cnt, N);
    final_lin<<<1, 128, 0, stream>>>(sums, cnt, Wl, bl, out);
}

// Round 11
// 473.740 us; speedup vs baseline: 1.0423x; 1.0114x over previous
//
#include <hip/hip_runtime.h>
#include <hip/hip_bf16.h>

// GCN: 3x gcn_conv + mean-pool + linear, bf16 MFMA pipeline.
// out[i] = dinv[i] * (sum_{e: dst=i} g[src_e] + g[i]) + b,  g = dinv .* (x @ W)

typedef __attribute__((ext_vector_type(8))) short short8_t;
typedef __attribute__((ext_vector_type(4))) float float4_t;

__device__ __forceinline__ unsigned short f2bf(float f) {
    unsigned int u = __float_as_uint(f);
    u += 0x7FFFu + ((u >> 16) & 1u);   // round-to-nearest-even
    return (unsigned short)(u >> 16);
}
__device__ __forceinline__ float bf2f(unsigned short h) {
    return __uint_as_float(((unsigned int)h) << 16);
}

// async global->LDS, 16B per lane; LDS dest is wave-uniform base + lane*16 (m104/m108)
#define GLDS16(gp, lp)                                                          \
    __builtin_amdgcn_global_load_lds(                                           \
        (const __attribute__((address_space(1))) void*)(gp),                    \
        (__attribute__((address_space(3))) void*)(lp), 16, 0, 0)

// ---------------- prep: conv_x + conv_weights + zero(indeg/sums/cnt), one launch ----------------
// Block-partitioned independent work; replaces 2 kernels + 1 memset node.

__global__ __launch_bounds__(256) void prep(const float* __restrict__ x,
                                            ushort* __restrict__ Xb,
                                            const float* __restrict__ W1, ushort* __restrict__ Wt1,
                                            const float* __restrict__ W2, ushort* __restrict__ Wt2,
                                            const float* __restrict__ W3, ushort* __restrict__ Wt3,
                                            int* __restrict__ zbase,
                                            int M, int Mpad, int nzero, int nxblk) {
    int bx = blockIdx.x;
    if (bx < nxblk) {                        // conv_x: fp32 x -> bf16 Xb (padded)
        int t = bx * 256 + threadIdx.x;      // one float4 -> ushort4
        int row = t >> 7;
        ushort4 o;
        if (row < M) {
            float4 v = ((const float4*)x)[t];
            o.x = f2bf(v.x); o.y = f2bf(v.y); o.z = f2bf(v.z); o.w = f2bf(v.w);
        } else {
            o.x = o.y = o.z = o.w = 0;
        }
        if (row < Mpad) ((ushort4*)Xb)[t] = o;
    } else if (bx < nxblk + 704) {           // weight transpose+convert
        int t = (bx - nxblk) * 256 + threadIdx.x;
        if (t < 131072) {                    // Wt1 [256][512]
            int k = t & 511, n = t >> 9;
            Wt1[t] = f2bf(W1[(size_t)k * 256 + n]);
        } else if (t < 163840) {             // Wt2 [128][256]
            int u = t - 131072;
            int k = u & 255, n = u >> 8;
            Wt2[u] = f2bf(W2[(size_t)k * 128 + n]);
        } else if (t < 180224) {             // Wt3 [128][128], N=64 (rows 64.. zero)
            int u = t - 163840;
            int k = u & 127, n = u >> 7;
            Wt3[u] = (n < 64) ? f2bf(W3[(size_t)k * 64 + n]) : (ushort)0;
        }
    } else {                                 // zero indeg + sums + cnt
        int t = (bx - nxblk - 704) * 256 + threadIdx.x;
        if (t < nzero) zbase[t] = 0;
    }
}

// ---------------- CSR build ----------------

__global__ void count_indeg(const int* __restrict__ dst, int* __restrict__ indeg, int E) {
    int e = blockIdx.x * blockDim.x + threadIdx.x;
    if (e < E) atomicAdd(&indeg[dst[e]], 1);
}

// hierarchical scan: per-1024-chunk inclusive -> chunk totals -> combine
__global__ __launch_bounds__(1024) void scan1(const int* __restrict__ indeg,
                                              int* __restrict__ incl,   // rowptr as temp
                                              int* __restrict__ part, int n) {
    __shared__ int sm[1024];
    int i = blockIdx.x * 1024 + threadIdx.x;
    int v = (i < n) ? indeg[i] : 0;
    sm[threadIdx.x] = v;
    __syncthreads();
    #pragma unroll
    for (int off = 1; off < 1024; off <<= 1) {
        int t = (threadIdx.x >= (unsigned)off) ? sm[threadIdx.x - off] : 0;
        __syncthreads();
        sm[threadIdx.x] += t;
        __syncthreads();
    }
    if (i < n) incl[i] = sm[threadIdx.x];
    if (threadIdx.x == 1023) part[blockIdx.x] = sm[1023];
}

// scan2 folded in: every block redundantly prefix-sums the <=64 chunk totals
// in its first wave (cheap), then applies. Also zeroes dinv pad rows.
__global__ __launch_bounds__(256) void scan23(const int* __restrict__ indeg,
                                              int* __restrict__ rowptr,
                                              int* __restrict__ cursor,
                                              const int* __restrict__ part,
                                              float* __restrict__ dinv,
                                              int n, int npad, int E, int nb) {
    __shared__ int ps[64];
    int tid = threadIdx.x;
    if (tid < 64) {
        int v = (tid < nb) ? part[tid] : 0;
        int orig = v;
        #pragma unroll
        for (int off = 1; off < 64; off <<= 1) {
            int u = __shfl_up(v, off, 64);
            if (tid >= off) v += u;
        }
        ps[tid] = v - orig;  // exclusive chunk offset
    }
    __syncthreads();
    int i = blockIdx.x * 256 + tid;
    if (i < n) {
        int excl = rowptr[i] - indeg[i] + ps[i >> 10];
        rowptr[i] = excl;
        cursor[i] = excl;
        dinv[i] = rsqrtf((float)indeg[i] + 1.0f);  // +1 self-loop
    } else if (i < npad) {
        dinv[i] = 0.f;                             // pad rows -> C rows are exact 0
    }
    if (i == 0) rowptr[n] = E;
}

__global__ void fill_csr(const int* __restrict__ src, const int* __restrict__ dst,
                         int* __restrict__ cursor, int* __restrict__ col, int E) {
    int e = blockIdx.x * blockDim.x + threadIdx.x;
    if (e < E) {
        int p = atomicAdd(&cursor[dst[e]], 1);
        col[p] = src[e];
    }
}

// ---------------- bf16 MFMA GEMM: C[m,n] = dinv[m] * sum_k A[m,k]*Bt[n,k] ----------------
// 128x128 tile, 256 threads = 4 waves (2x2), each wave 4x4 tiles of 16x16x32.
// Double-buffered global_load_lds staging. Stores ALL Mpad rows (pad rows have
// A=0, dinv=0 -> exact zeros) so row N is a valid zero-gather target for agg.

__device__ __forceinline__ void mfma_step(const ushort* __restrict__ Asb,
                                          const ushort* __restrict__ Bsb,
                                          int arow, int brow, int quad,
                                          float4_t (&acc)[4][4]) {
    short8_t aF[4], bF[4];
    #pragma unroll
    for (int i = 0; i < 4; ++i)
        aF[i] = *(const short8_t*)&Asb[(arow + i * 16) * 32 + quad * 8];
    #pragma unroll
    for (int j = 0; j < 4; ++j)
        bF[j] = *(const short8_t*)&Bsb[(brow + j * 16) * 32 + quad * 8];
    #pragma unroll
    for (int i = 0; i < 4; ++i)
        #pragma unroll
        for (int j = 0; j < 4; ++j)
            acc[i][j] = __builtin_amdgcn_mfma_f32_16x16x32_bf16(aF[i], bF[j], acc[i][j], 0, 0, 0);
}

__global__ __launch_bounds__(256) void gemm_mfma(const ushort* __restrict__ A,
                                                 const ushort* __restrict__ Bt,
                                                 const float* __restrict__ dinv,
                                                 ushort* __restrict__ C,
                                                 int Ncols, int K, int ldc) {
    __shared__ __align__(16) ushort As[2 * 4096];
    __shared__ __align__(16) ushort Bs[2 * 4096];
    int tid = threadIdx.x;
    int lane = tid & 63, w = tid >> 6;
    int wr = w >> 1, wc = w & 1;
    int bm = blockIdx.x * 128, bn = blockIdx.y * 128;

    float4_t acc[4][4];
    #pragma unroll
    for (int i = 0; i < 4; ++i)
        #pragma unroll
        for (int j = 0; j < 4; ++j) acc[i][j] = (float4_t)0.0f;

    int r0 = tid >> 2;
    int kb = (tid & 3) * 8;
    const ushort* ga0 = A + (size_t)(bm + r0) * K + kb;
    const ushort* ga1 = A + (size_t)(bm + r0 + 64) * K + kb;
    const ushort* gb0 = Bt + (size_t)(bn + r0) * K + kb;
    const ushort* gb1 = Bt + (size_t)(bn + r0 + 64) * K + kb;
    int w512 = w * 512;

#define ISSUE_DMA(kk, bufofs)                              \
    do {                                                   \
        GLDS16(ga0 + (kk), As + (bufofs) + w512);          \
        GLDS16(ga1 + (kk), As + (bufofs) + 2048 + w512);   \
        GLDS16(gb0 + (kk), Bs + (bufofs) + w512);          \
        GLDS16(gb1 + (kk), Bs + (bufofs) + 2048 + w512);   \
    } while (0)

    int arow = wr * 64 + (lane & 15);
    int brow = wc * 64 + (lane & 15);
    int quad = lane >> 4;

    ISSUE_DMA(0, 0);  // prologue -> buf0
    for (int k0 = 0; k0 < K; k0 += 64) {
        __syncthreads();                      // buf0 tile (k0) published
        ISSUE_DMA(k0 + 32, 4096);             // next tile -> buf1 (k0+32 < K always)
        mfma_step(As, Bs, arow, brow, quad, acc);
        __syncthreads();                      // buf1 tile (k0+32) published
        if (k0 + 64 < K) ISSUE_DMA(k0 + 64, 0);
        mfma_step(As + 4096, Bs + 4096, arow, brow, quad, acc);
    }
#undef ISSUE_DMA

    // C/D layout: col = lane&15, row = (lane>>4)*4 + reg
    int colb = bn + wc * 64 + (lane & 15);
    #pragma unroll
    for (int i = 0; i < 4; ++i) {
        int mb = bm + wr * 64 + i * 16 + quad * 4;
        #pragma unroll
        for (int r = 0; r < 4; ++r) {
            int m = mb + r;
            float s = dinv[m];
            #pragma unroll
            for (int j = 0; j < 4; ++j) {
                int n = colb + j * 16;
                if (n < Ncols) C[(size_t)m * ldc + n] = f2bf(acc[i][j][r] * s);
            }
        }
    }
}

// ---------------- aggregation: edge-packed, bf16 in/out ----------------
// One wave per node, EPL edges share each load instruction. Pad lanes hold
// zrow (guaranteed-zero row) -> no masks. Cross-half shfl_xor folds partials.
// FETCH ~186 MB is the random-graph XCD-topology floor (7.05 XCDs/row).

template <int DW> struct VecT;
template <> struct VecT<2> { using type = uint2; };
template <> struct VecT<4> { using type = uint4; };

template <int F, bool RELU>
__global__ __launch_bounds__(256) void agg_bf(const ushort* __restrict__ g,
                                              const int* __restrict__ rowptr,
                                              const int* __restrict__ col,
                                              const float* __restrict__ dinv,
                                              const float* __restrict__ bias,
                                              ushort* __restrict__ out,
                                              int n, int npad, int zrow) {
    constexpr int EPL  = (F == 64) ? 4 : 2;  // edges per load instruction
    constexpr int SUBW = 64 / EPL;           // lanes per edge
    constexpr int EPT  = F / SUBW;           // elements per lane
    constexpr int LPG  = 16 / EPL;           // loads per 16-edge flight group
    constexpr int DW   = EPT / 2;            // dwords per load
    using vec_t = typename VecT<DW>::type;

    int wid = (int)((blockIdx.x * blockDim.x + threadIdx.x) >> 6);
    int lane = threadIdx.x & 63;
    if (wid >= npad) return;
    int h   = lane / SUBW;                   // edge slot within a load (0..EPL-1)
    int sub = lane & (SUBW - 1);
    int off = sub * EPT;
    ushort* orow = out + (size_t)wid * F + off;

    if (wid >= n) {  // zero padded tail rows (zero-gather targets + next GEMM A)
        if (h == 0) {
            #pragma unroll
            for (int d = 0; d < DW; ++d) ((uint*)orow)[d] = 0;
        }
        return;
    }

    // self row: issue early; identical across h-slots (same addresses)
    const ushort* gofs = g + off;
    vec_t sv = *(const vec_t*)(gofs + (size_t)wid * F);
    float self[EPT];
    #pragma unroll
    for (int d = 0; d < DW; ++d) {
        uint dw = ((const uint*)&sv)[d];
        self[2 * d]     = __uint_as_float(dw << 16);
        self[2 * d + 1] = __uint_as_float(dw & 0xffff0000u);
    }

    float acc[EPT];
    #pragma unroll
    for (int t = 0; t < EPT; ++t) acc[t] = 0.f;

    int e0 = rowptr[wid];
    int deg = rowptr[wid + 1] - e0;

    for (int base = 0; base < deg; base += 64) {
        int cnt = min(64, deg - base);
        int ec = (lane < cnt) ? col[e0 + base + lane] : zrow;  // pad lanes -> zero row
        for (int j = 0; j < cnt; j += 16) {
            vec_t v[LPG];
            #pragma unroll
            for (int u = 0; u < LPG; ++u) {
                int id = __shfl(ec, j + u * EPL + h);          // <=j+15<64; pad->zrow
                v[u] = *(const vec_t*)(gofs + (size_t)id * F);
            }
            #pragma unroll
            for (int u = 0; u < LPG; ++u)
                #pragma unroll
                for (int d = 0; d < DW; ++d) {
                    uint dw = ((const uint*)&v[u])[d];
                    acc[2 * d]     += __uint_as_float(dw << 16);
                    acc[2 * d + 1] += __uint_as_float(dw & 0xffff0000u);
                }
        }
    }

    // fold edge slots: lanes differing only in h hold the same features
    #pragma unroll
    for (int t = 0; t < EPT; ++t) {
        if constexpr (EPL == 4) acc[t] += __shfl_xor(acc[t], 16, 64);
        acc[t] += __shfl_xor(acc[t], 32, 64);
    }

    float di = dinv[wid];
    ushort res[EPT];
    #pragma unroll
    for (int t = 0; t < EPT; ++t) {
        float r = di * (acc[t] + self[t]) + bias[off + t];
        if (RELU) r = fmaxf(r, 0.f);
        res[t] = f2bf(r);
    }
    if (h == 0) {
        #pragma unroll
        for (int d = 0; d < DW; ++d)
            ((uint*)orow)[d] = (uint)res[2 * d] | ((uint)res[2 * d + 1] << 16);
    }
}

// ---------------- pooling + final linear ----------------

__global__ __launch_bounds__(256) void pool_sorted(const ushort* __restrict__ h,
                                                   const int* __restrict__ batch,
                                                   float* __restrict__ sums,
                                                   float* __restrict__ cnt, int n) {
    int wave = (int)((blockIdx.x * blockDim.x + threadIdx.x) >> 6);
    int lane = threadIdx.x & 63;
    int start = wave * 64;
    if (start >= n) return;
    int end = min(start + 64, n);
    float acc = 0.f;
    int cur = batch[start];
    int runlen = 0;
    for (int i = start; i < end; ++i) {
        int b = batch[i];
        if (b != cur) {
            atomicAdd(&sums[cur * 64 + lane], acc);
            if (lane == 0) atomicAdd(&cnt[cur], (float)runlen);
            acc = 0.f;
            runlen = 0;
            cur = b;
        }
        acc += bf2f(h[(size_t)i * 64 + lane]);
        runlen++;
    }
    atomicAdd(&sums[cur * 64 + lane], acc);
    if (lane == 0) atomicAdd(&cnt[cur], (float)runlen);
}

__global__ void final_lin(const float* __restrict__ sums, const float* __restrict__ cnt,
                          const float* __restrict__ Wl, const float* __restrict__ bl,
                          float* __restrict__ out) {
    int t = threadIdx.x;  // 128 threads: (graph, j)
    int g = t >> 1, j = t & 1;
    float c = fmaxf(cnt[g], 1.0f);
    float a = 0.f;
    #pragma unroll
    for (int k = 0; k < 64; ++k) a += sums[g * 64 + k] * Wl[k * 2 + j];
    out[t] = a / c + bl[j];
}

// ---------------- launch ----------------

extern "C" void kernel_launch(void* const* d_in, const int* in_sizes, int n_in,
                              void* d_out, int out_size, void* d_ws, size_t ws_size,
                              hipStream_t stream) {
    const float* x   = (const float*)d_in[0];
    const int*   ei  = (const int*)d_in[1];
    const int*   bat = (const int*)d_in[2];
    const float* W1  = (const float*)d_in[3];
    const float* b1  = (const float*)d_in[4];
    const float* W2  = (const float*)d_in[5];
    const float* b2  = (const float*)d_in[6];
    const float* W3  = (const float*)d_in[7];
    const float* b3  = (const float*)d_in[8];
    const float* Wl  = (const float*)d_in[9];
    const float* bl  = (const float*)d_in[10];
    float* out = (float*)d_out;

    const int N = in_sizes[0] / 512;
    const int E = in_sizes[1] / 2;
    const int Mpad = ((N + 127) / 128) * 128;   // 50048
    const int* src = ei;
    const int* dst = ei + E;

    char* w = (char*)d_ws;
    auto alloc = [&](size_t bytes) {
        char* p = w;
        w += (bytes + 255) & ~(size_t)255;
        return p;
    };
    ushort* Xb   = (ushort*)alloc((size_t)Mpad * 512 * 2);  // bf16 x (L3-resident)
    ushort* G    = (ushort*)alloc((size_t)Mpad * 256 * 2);  // gemm output
    ushort* H    = (ushort*)alloc((size_t)Mpad * 256 * 2);  // agg output
    ushort* Wt1  = (ushort*)alloc(256 * 512 * 2);
    ushort* Wt2  = (ushort*)alloc(128 * 256 * 2);
    ushort* Wt3  = (ushort*)alloc(128 * 128 * 2);
    float* dinv  = (float*)alloc((size_t)Mpad * 4);
    int* rowptr  = (int*)alloc((size_t)(N + 1) * 4);
    int* cursor  = (int*)alloc((size_t)N * 4);
    int* col     = (int*)alloc((size_t)(E + 16) * 4);
    int* part    = (int*)alloc(256 * 4);
    int nzero = N + 64 * 64 + 64;               // indeg + sums + cnt (ints/floats)
    int* indeg   = (int*)alloc((size_t)nzero * 4);
    float* sums  = (float*)(indeg + N);
    float* cnt   = sums + 64 * 64;

    // prep: conv_x + weight converts + zeroing, one launch
    int nxblk = (Mpad * 128 + 255) / 256;       // conv_x blocks (t = float4 index)
    int nzblk = (nzero + 255) / 256;
    prep<<<nxblk + 704 + nzblk, 256, 0, stream>>>(x, Xb, W1, Wt1, W2, Wt2, W3, Wt3,
                                                  indeg, N, Mpad, nzero, nxblk);

    // CSR
    count_indeg<<<(E + 255) / 256, 256, 0, stream>>>(dst, indeg, E);
    int nb = (N + 1023) / 1024;
    scan1<<<nb, 1024, 0, stream>>>(indeg, rowptr, part, N);
    scan23<<<(Mpad + 255) / 256, 256, 0, stream>>>(indeg, rowptr, cursor, part, dinv,
                                                   N, Mpad, E, nb);
    fill_csr<<<(E + 255) / 256, 256, 0, stream>>>(src, dst, cursor, col, E);

    int npad = Mpad;
    // layer 1: 512 -> 256
    gemm_mfma<<<dim3(Mpad / 128, 2), 256, 0, stream>>>(Xb, Wt1, dinv, G, 256, 512, 256);
    agg_bf<256, true><<<npad / 4, 256, 0, stream>>>(G, rowptr, col, dinv, b1, H, N, npad, N);
    // layer 2: 256 -> 128
    gemm_mfma<<<dim3(Mpad / 128, 1), 256, 0, stream>>>(H, Wt2, dinv, G, 128, 256, 128);
    agg_bf<128, true><<<npad / 4, 256, 0, stream>>>(G, rowptr, col, dinv, b2, H, N, npad, N);
    // layer 3: 128 -> 64 (Wt3 padded to 128 rows, store guarded n<64)
    gemm_mfma<<<dim3(Mpad / 128, 1), 256, 0, stream>>>(H, Wt3, dinv, G, 64, 128, 64);
    agg_bf<64, false><<<npad / 4, 256, 0, stream>>>(G, rowptr, col, dinv, b3, H, N, npad, N);

    pool_sorted<<<(N + 255) / 256, 256, 0, stream>>>(H, bat, sums, cnt, N);
    final_lin<<<1, 128, 0, stream>>>(sums, cnt, Wl, bl, out);
}